// Round 1
// baseline (1720.832 us; speedup 1.0000x reference)
//
#include <hip/hip_runtime.h>
#include <stdint.h>
#include <stddef.h>

typedef unsigned short u16;
typedef float f4 __attribute__((ext_vector_type(4)));
typedef float f32x4 __attribute__((ext_vector_type(4)));
typedef short bf16x8 __attribute__((ext_vector_type(8)));
typedef u16 u16x4 __attribute__((ext_vector_type(4)));
typedef int i4v __attribute__((ext_vector_type(4)));

#define PAD_TOK 1026
#define LQ 61
#define NBATCH 256
#define MTOT (NBATCH * LQ)   // 15616 = 122*128

__device__ __forceinline__ u16 f2b(float f) {
  uint32_t x = __float_as_uint(f);
  x += 0x7fff + ((x >> 16) & 1);   // RNE
  return (u16)(x >> 16);
}

// ---------------------------------------------------------------------------
// Generic bf16 B^T GEMM: C[m][n] = sum_k A[m][k] * W[n][k] + bias[n] (+resid)
// 128x128 tile, BK=64, 4 waves, global_load_lds(16B) with XOR-swizzled source
// (linear LDS dest, swizzled ds_read: rule-21-compliant).
// ---------------------------------------------------------------------------
__global__ __launch_bounds__(256) void gemm_bt(
    const u16* __restrict__ A, const u16* __restrict__ W,
    const float* __restrict__ bias, const float* __restrict__ resid,
    float* __restrict__ Cf, u16* __restrict__ Cb,
    int M, int N, int K, int Nreal, int ldc, int relu,
    long aZ, long wZ, long bZ, long cZ)
{
  const int z = blockIdx.z;
  A += z * aZ; W += z * wZ; bias += z * bZ;
  if (Cf) Cf += z * cZ;
  if (Cb) Cb += z * cZ;

  __shared__ u16 As[128 * 64];
  __shared__ u16 Bs[128 * 64];

  const int tid = threadIdx.x;
  const int wid = tid >> 6, lane = tid & 63;
  const int wr = wid >> 1, wc = wid & 1;
  const long m0 = (long)blockIdx.y * 128;
  const long n0 = (long)blockIdx.x * 128;

  const int lr = lane >> 3;              // row-in-8 for staging
  const int lc = lane & 7;               // 16B chunk
  const int scol = ((lc ^ lr) << 3);     // pre-swizzled source col (elems)

  f32x4 acc[4][4];
#pragma unroll
  for (int i = 0; i < 4; ++i)
#pragma unroll
    for (int j = 0; j < 4; ++j) acc[i][j] = (f32x4){0.f, 0.f, 0.f, 0.f};

  const u16* Abase = A + m0 * K;
  const u16* Wbase = W + n0 * K;
  const int r = lane & 15, kg = lane >> 4;

  for (int kt = 0; kt < K; kt += 64) {
#pragma unroll
    for (int c = 0; c < 4; ++c) {
      const int row = wid * 32 + c * 8;          // wave-uniform base row
      __builtin_amdgcn_global_load_lds(
          (const __attribute__((address_space(1))) void*)(Abase + (long)(row + lr) * K + kt + scol),
          (__attribute__((address_space(3))) void*)&As[row * 64], 16, 0, 0);
      __builtin_amdgcn_global_load_lds(
          (const __attribute__((address_space(1))) void*)(Wbase + (long)(row + lr) * K + kt + scol),
          (__attribute__((address_space(3))) void*)&Bs[row * 64], 16, 0, 0);
    }
    __syncthreads();   // compiler emits vmcnt(0)+lgkmcnt(0) drain here

#pragma unroll
    for (int ks = 0; ks < 64; ks += 32) {
      bf16x8 a[4], b[4];
#pragma unroll
      for (int mi = 0; mi < 4; ++mi) {
        const int row = wr * 64 + mi * 16 + r;
        const int chunk = ((ks >> 3) + kg) ^ (row & 7);
        a[mi] = *(const bf16x8*)&As[row * 64 + chunk * 8];
      }
#pragma unroll
      for (int ni = 0; ni < 4; ++ni) {
        const int row = wc * 64 + ni * 16 + r;
        const int chunk = ((ks >> 3) + kg) ^ (row & 7);
        b[ni] = *(const bf16x8*)&Bs[row * 64 + chunk * 8];
      }
#pragma unroll
      for (int mi = 0; mi < 4; ++mi)
#pragma unroll
        for (int ni = 0; ni < 4; ++ni)
          acc[mi][ni] = __builtin_amdgcn_mfma_f32_16x16x32_bf16(a[mi], b[ni], acc[mi][ni], 0, 0, 0);
    }
    __syncthreads();
  }

  // epilogue: C row = (lane>>4)*4+j, col = lane&15  (verified m89 layout)
  const int cr = (lane >> 4) * 4;
  const int cc = lane & 15;
#pragma unroll
  for (int ni = 0; ni < 4; ++ni) {
    const int n = (int)n0 + wc * 64 + ni * 16 + cc;
    if (n >= Nreal) continue;
    const float bv = bias[n];
#pragma unroll
    for (int mi = 0; mi < 4; ++mi) {
#pragma unroll
      for (int j = 0; j < 4; ++j) {
        const long m = m0 + wr * 64 + mi * 16 + cr + j;
        float v = acc[mi][ni][j] + bv;
        if (resid) v += resid[m * 512 + n];
        if (relu) v = fmaxf(v, 0.f);
        if (Cf) Cf[m * ldc + n] = v;
        if (Cb) Cb[m * (long)N + n] = f2b(v);
      }
    }
  }
}

// ---------------------------------------------------------------------------
// Fused self-attention: one block per (batch, head). 61 queries/keys padded
// to 64. MFMA for QK^T and PV; softmax via LDS + 4-lane shfl groups.
// ---------------------------------------------------------------------------
__global__ __launch_bounds__(256) void attn_k(const u16* __restrict__ qkv,
                                              const int* __restrict__ tgt,
                                              u16* __restrict__ outp)
{
  __shared__ u16 Qs[64 * 72];   // also reused as P (bf16)
  __shared__ u16 Ks[64 * 72];
  __shared__ u16 Vt[64 * 72];   // V^T: rows d, cols k
  __shared__ float S[64 * 65];
  __shared__ int stok[64];

  const int bid = blockIdx.x;
  const int b = bid >> 3, h = bid & 7;
  const int tid = threadIdx.x;
  const int tr = tid >> 2, seg = tid & 3;

  if (tid < 64) stok[tid] = (tid < 61) ? tgt[b * 62 + tid] : -1;

  const long rowbase = ((long)(b * LQ + tr)) * 1536 + h * 64;
  if (tr < LQ) {
    const i4v* qsrc = (const i4v*)(qkv + rowbase + seg * 16);
    i4v q0 = qsrc[0], q1 = qsrc[1];
    *(i4v*)&Qs[tr * 72 + seg * 16] = q0;
    *(i4v*)&Qs[tr * 72 + seg * 16 + 8] = q1;
    const i4v* ksrc = (const i4v*)(qkv + rowbase + 512 + seg * 16);
    i4v k0 = ksrc[0], k1 = ksrc[1];
    *(i4v*)&Ks[tr * 72 + seg * 16] = k0;
    *(i4v*)&Ks[tr * 72 + seg * 16 + 8] = k1;
    const u16* vsrc = qkv + rowbase + 1024 + seg * 16;
#pragma unroll
    for (int i = 0; i < 16; ++i) Vt[(seg * 16 + i) * 72 + tr] = vsrc[i];
  } else {
    i4v zz = {0, 0, 0, 0};
    *(i4v*)&Qs[tr * 72 + seg * 16] = zz;
    *(i4v*)&Qs[tr * 72 + seg * 16 + 8] = zz;
    *(i4v*)&Ks[tr * 72 + seg * 16] = zz;
    *(i4v*)&Ks[tr * 72 + seg * 16 + 8] = zz;
#pragma unroll
    for (int i = 0; i < 16; ++i) Vt[(seg * 16 + i) * 72 + tr] = 0;
  }
  __syncthreads();

  const int lane = tid & 63, w = tid >> 6;
  const int r = lane & 15, kg = lane >> 4;

  {   // QK^T: wave w computes S rows [16w,16w+16)
    f32x4 s[4];
#pragma unroll
    for (int ni = 0; ni < 4; ++ni) s[ni] = (f32x4){0.f, 0.f, 0.f, 0.f};
    bf16x8 a0 = *(const bf16x8*)&Qs[(w * 16 + r) * 72 + kg * 8];
    bf16x8 a1 = *(const bf16x8*)&Qs[(w * 16 + r) * 72 + 32 + kg * 8];
#pragma unroll
    for (int ni = 0; ni < 4; ++ni) {
      bf16x8 b0 = *(const bf16x8*)&Ks[(ni * 16 + r) * 72 + kg * 8];
      bf16x8 b1 = *(const bf16x8*)&Ks[(ni * 16 + r) * 72 + 32 + kg * 8];
      s[ni] = __builtin_amdgcn_mfma_f32_16x16x32_bf16(a0, b0, s[ni], 0, 0, 0);
      s[ni] = __builtin_amdgcn_mfma_f32_16x16x32_bf16(a1, b1, s[ni], 0, 0, 0);
    }
#pragma unroll
    for (int ni = 0; ni < 4; ++ni)
#pragma unroll
      for (int j = 0; j < 4; ++j)
        S[(w * 16 + kg * 4 + j) * 65 + ni * 16 + r] = s[ni][j];
  }
  __syncthreads();

  {   // masked softmax, 4 lanes per row, 16 cols each; P -> Qs (bf16)
    const int row = tid >> 2, g = tid & 3;
    float vals[16];
    float mx = -3e38f;
#pragma unroll
    for (int i = 0; i < 16; ++i) {
      const int k = g * 16 + i;
      float v = S[row * 65 + k] * 0.125f;
      const bool ok = (k <= row) && (k < LQ) && (stok[k] != PAD_TOK);
      v = ok ? v : -1e30f;
      vals[i] = v;
      mx = fmaxf(mx, v);
    }
    mx = fmaxf(mx, __shfl_xor(mx, 1));
    mx = fmaxf(mx, __shfl_xor(mx, 2));
    float sum = 0.f;
#pragma unroll
    for (int i = 0; i < 16; ++i) { float e = __expf(vals[i] - mx); vals[i] = e; sum += e; }
    sum += __shfl_xor(sum, 1);
    sum += __shfl_xor(sum, 2);
    const float inv = 1.f / sum;
#pragma unroll
    for (int i = 0; i < 16; ++i) Qs[row * 72 + g * 16 + i] = f2b(vals[i] * inv);
  }
  __syncthreads();

  {   // PV: O rows [16w,16w+16), cols d = ni*16+r
    f32x4 o[4];
#pragma unroll
    for (int ni = 0; ni < 4; ++ni) o[ni] = (f32x4){0.f, 0.f, 0.f, 0.f};
    bf16x8 a0 = *(const bf16x8*)&Qs[(w * 16 + r) * 72 + kg * 8];
    bf16x8 a1 = *(const bf16x8*)&Qs[(w * 16 + r) * 72 + 32 + kg * 8];
#pragma unroll
    for (int ni = 0; ni < 4; ++ni) {
      bf16x8 b0 = *(const bf16x8*)&Vt[(ni * 16 + r) * 72 + kg * 8];
      bf16x8 b1 = *(const bf16x8*)&Vt[(ni * 16 + r) * 72 + 32 + kg * 8];
      o[ni] = __builtin_amdgcn_mfma_f32_16x16x32_bf16(a0, b0, o[ni], 0, 0, 0);
      o[ni] = __builtin_amdgcn_mfma_f32_16x16x32_bf16(a1, b1, o[ni], 0, 0, 0);
    }
#pragma unroll
    for (int ni = 0; ni < 4; ++ni)
#pragma unroll
      for (int j = 0; j < 4; ++j) {
        const int q = w * 16 + kg * 4 + j;
        if (q < LQ)
          outp[((long)(b * LQ + q)) * 512 + h * 64 + ni * 16 + r] = f2b(o[ni][j]);
      }
  }
}

// ---------------------------------------------------------------------------
// LayerNorm over D=512: one wave per row, 8 elems/lane. Optional broadcast
// add (cross-attn vector per batch). Writes f32 x and bf16 mirror.
// ---------------------------------------------------------------------------
__global__ __launch_bounds__(256) void ln_k(const float* __restrict__ src,
                                            const float* __restrict__ bcast,
                                            const float* __restrict__ sw,
                                            const float* __restrict__ bw,
                                            float* __restrict__ X,
                                            u16* __restrict__ XB)
{
  const int m = blockIdx.x * 4 + (threadIdx.x >> 6);
  const int lane = threadIdx.x & 63;
  const int d0 = lane * 8;
  const f4* p = (const f4*)(src + (long)m * 512 + d0);
  f4 v0 = p[0], v1 = p[1];
  if (bcast) {
    const int b = m / LQ;
    const f4* q = (const f4*)(bcast + (long)b * 512 + d0);
    v0 += q[0]; v1 += q[1];
  }
  float s1 = v0[0] + v0[1] + v0[2] + v0[3] + v1[0] + v1[1] + v1[2] + v1[3];
  float s2 = v0[0]*v0[0] + v0[1]*v0[1] + v0[2]*v0[2] + v0[3]*v0[3]
           + v1[0]*v1[0] + v1[1]*v1[1] + v1[2]*v1[2] + v1[3]*v1[3];
#pragma unroll
  for (int off = 1; off < 64; off <<= 1) {
    s1 += __shfl_xor(s1, off);
    s2 += __shfl_xor(s2, off);
  }
  const float mean = s1 * (1.f / 512.f);
  const float var = s2 * (1.f / 512.f) - mean * mean;
  const float rstd = rsqrtf(var + 1e-5f);
  const f4* sp = (const f4*)(sw + d0);
  const f4* bp = (const f4*)(bw + d0);
  f4 ss0 = sp[0], ss1 = sp[1], bb0 = bp[0], bb1 = bp[1];
  f4 y0, y1;
#pragma unroll
  for (int i = 0; i < 4; ++i) {
    y0[i] = (v0[i] - mean) * rstd * ss0[i] + bb0[i];
    y1[i] = (v1[i] - mean) * rstd * ss1[i] + bb1[i];
  }
  f4* xo = (f4*)(X + (long)m * 512 + d0);
  xo[0] = y0; xo[1] = y1;
  u16x4 h0 = {f2b(y0[0]), f2b(y0[1]), f2b(y0[2]), f2b(y0[3])};
  u16x4 h1 = {f2b(y1[0]), f2b(y1[1]), f2b(y1[2]), f2b(y1[3])};
  u16x4* xb = (u16x4*)(XB + (long)m * 512 + d0);
  xb[0] = h0; xb[1] = h1;
}

// Embedding: x[m] = emb[tok] + point_out[b] + pos_embed[t]
__global__ __launch_bounds__(256) void embed_k(const float* __restrict__ emb,
                                               const float* __restrict__ pout,
                                               const float* __restrict__ pos,
                                               const int* __restrict__ tgt,
                                               float* __restrict__ X,
                                               u16* __restrict__ XB)
{
  const int m = blockIdx.x * 4 + (threadIdx.x >> 6);
  const int lane = threadIdx.x & 63;
  const int b = m / LQ, t = m % LQ;
  const int tok = tgt[b * 62 + t];
  const int d0 = lane * 8;
  const f4* e = (const f4*)(emb + (long)tok * 512 + d0);
  const f4* p = (const f4*)(pout + (long)b * 512 + d0);
  const f4* q = (const f4*)(pos + (long)t * 512 + d0);
  f4 v0 = e[0] + p[0] + q[0];
  f4 v1 = e[1] + p[1] + q[1];
  f4* xo = (f4*)(X + (long)m * 512 + d0);
  xo[0] = v0; xo[1] = v1;
  u16x4 h0 = {f2b(v0[0]), f2b(v0[1]), f2b(v0[2]), f2b(v0[3])};
  u16x4 h1 = {f2b(v1[0]), f2b(v1[1]), f2b(v1[2]), f2b(v1[3])};
  u16x4* xb = (u16x4*)(XB + (long)m * 512 + d0);
  xb[0] = h0; xb[1] = h1;
}

// f32 -> bf16 converters
__global__ void cvt_bf16_k(const float* __restrict__ src, u16* __restrict__ dst, int n4) {
  const int i = blockIdx.x * 256 + threadIdx.x;
  if (i >= n4) return;
  f4 v = ((const f4*)src)[i];
  ((u16x4*)dst)[i] = (u16x4){f2b(v[0]), f2b(v[1]), f2b(v[2]), f2b(v[3])};
}

// ca_inw v-slice (rows 1024..1535 of each layer's [1536][512])
__global__ void cvt_ca_v_k(const float* __restrict__ ca_inw, u16* __restrict__ dst) {
  const int i = blockIdx.x * 256 + threadIdx.x;
  if (i >= 393216) return;                  // 6*512*512/4
  const int l = i >> 16, rem = i & 65535;   // 65536 f4 per layer slice
  f4 v = ((const f4*)ca_inw)[l * 196608 + 131072 + rem];
  ((u16x4*)dst)[i] = (u16x4){f2b(v[0]), f2b(v[1]), f2b(v[2]), f2b(v[3])};
}

// out_w padded to [1152][512] bf16, rows >=1027 zero
__global__ void cvt_outw_k(const float* __restrict__ out_w, u16* __restrict__ dst) {
  const int i = blockIdx.x * 256 + threadIdx.x;
  if (i >= 147456) return;                  // 1152*512/4
  const int row = (i * 4) >> 9;
  u16x4 o = {0, 0, 0, 0};
  if (row < 1027) {
    f4 v = ((const f4*)out_w)[i];
    o = (u16x4){f2b(v[0]), f2b(v[1]), f2b(v[2]), f2b(v[3])};
  }
  ((u16x4*)dst)[i] = o;
}

__global__ void cvt_outb_k(const float* __restrict__ out_b, float* __restrict__ dst) {
  const int i = blockIdx.x * 256 + threadIdx.x;
  if (i >= 1152) return;
  dst[i] = (i < 1027) ? out_b[i] : 0.f;
}

// mem = encoder_out[:, 0, :] -> bf16 [256][512]
__global__ void cvt_memb_k(const float* __restrict__ enc, u16* __restrict__ dst) {
  const int i = blockIdx.x * 256 + threadIdx.x;
  if (i >= 32768) return;                   // 256*512/4
  const int b = (i * 4) >> 9, d = (i * 4) & 511;
  f4 v = ((const f4*)enc)[(b * 8192 + d) >> 2];
  ((u16x4*)dst)[i] = (u16x4){f2b(v[0]), f2b(v[1]), f2b(v[2]), f2b(v[3])};
}

// ---------------------------------------------------------------------------
// Workspace layout (bytes)
// ---------------------------------------------------------------------------
static constexpr size_t XB_OFF    = 0;                       // bf16 [15616][512]
static constexpr size_t X_OFF     = 15990784;                // f32  [15616][512]
static constexpr size_t BIG_OFF   = 47972352;                // bf16 qkv[15616][1536] / h1[15616][2048]
static constexpr size_t ATT_OFF   = 111935488;               // bf16 [15616][512]
static constexpr size_t WSA_OFF   = 127926272;               // bf16 [6][1536][512]
static constexpr size_t WSO_OFF   = 137363456;               // bf16 [6][512][512]
static constexpr size_t WCAV_OFF  = 140509184;               // bf16 [6][512][512]
static constexpr size_t WCO_OFF   = 143654912;               // bf16 [6][512][512]
static constexpr size_t WF1_OFF   = 146800640;               // bf16 [6][2048][512]
static constexpr size_t WF2_OFF   = 159383552;               // bf16 [6][512][2048]
static constexpr size_t WOUT_OFF  = 171966464;               // bf16 [1152][512]
static constexpr size_t BOUT_OFF  = 173146112;               // f32  [1152]
static constexpr size_t MEMB_OFF  = 173150720;               // bf16 [256][512]
static constexpr size_t CATMP_OFF = 173412864;               // bf16 [6][256][512]
static constexpr size_t CAV_OFF   = 174985728;               // f32  [6][256][512]

extern "C" void kernel_launch(void* const* d_in, const int* in_sizes, int n_in,
                              void* d_out, int out_size, void* d_ws, size_t ws_size,
                              hipStream_t stream) {
  (void)in_sizes; (void)n_in; (void)out_size; (void)ws_size;
  const float* encoder_out = (const float*)d_in[0];
  const float* point_out   = (const float*)d_in[1];
  const float* emb         = (const float*)d_in[2];
  const float* pos         = (const float*)d_in[3];
  const float* sa_inw      = (const float*)d_in[4];
  const float* sa_inb      = (const float*)d_in[5];
  const float* sa_outw     = (const float*)d_in[6];
  const float* sa_outb     = (const float*)d_in[7];
  const float* ca_inw      = (const float*)d_in[8];
  const float* ca_inb      = (const float*)d_in[9];
  const float* ca_outw     = (const float*)d_in[10];
  const float* ca_outb     = (const float*)d_in[11];
  const float* ln1_s       = (const float*)d_in[12];
  const float* ln1_b       = (const float*)d_in[13];
  const float* ln2_s       = (const float*)d_in[14];
  const float* ln2_b       = (const float*)d_in[15];
  const float* ln3_s       = (const float*)d_in[16];
  const float* ln3_b       = (const float*)d_in[17];
  const float* ff1_w       = (const float*)d_in[18];
  const float* ff1_b       = (const float*)d_in[19];
  const float* ff2_w       = (const float*)d_in[20];
  const float* ff2_b       = (const float*)d_in[21];
  const float* out_w       = (const float*)d_in[22];
  const float* out_b       = (const float*)d_in[23];
  const int*   tgt         = (const int*)d_in[24];

  char* ws = (char*)d_ws;
  u16*   XB    = (u16*)(ws + XB_OFF);
  float* X     = (float*)(ws + X_OFF);
  u16*   BIG   = (u16*)(ws + BIG_OFF);
  u16*   ATT   = (u16*)(ws + ATT_OFF);
  u16*   WSA   = (u16*)(ws + WSA_OFF);
  u16*   WSO   = (u16*)(ws + WSO_OFF);
  u16*   WCAV  = (u16*)(ws + WCAV_OFF);
  u16*   WCO   = (u16*)(ws + WCO_OFF);
  u16*   WF1   = (u16*)(ws + WF1_OFF);
  u16*   WF2   = (u16*)(ws + WF2_OFF);
  u16*   WOUT  = (u16*)(ws + WOUT_OFF);
  float* BOUT  = (float*)(ws + BOUT_OFF);
  u16*   MEMB  = (u16*)(ws + MEMB_OFF);
  u16*   CATMP = (u16*)(ws + CATMP_OFF);
  float* CAV   = (float*)(ws + CAV_OFF);

  // ---- weight conversion (per call; deterministic) ----
  cvt_bf16_k<<<dim3(4608), dim3(256), 0, stream>>>(sa_inw, WSA, 1179648);
  cvt_bf16_k<<<dim3(1536), dim3(256), 0, stream>>>(sa_outw, WSO, 393216);
  cvt_ca_v_k<<<dim3(1536), dim3(256), 0, stream>>>(ca_inw, WCAV);
  cvt_bf16_k<<<dim3(1536), dim3(256), 0, stream>>>(ca_outw, WCO, 393216);
  cvt_bf16_k<<<dim3(6144), dim3(256), 0, stream>>>(ff1_w, WF1, 1572864);
  cvt_bf16_k<<<dim3(6144), dim3(256), 0, stream>>>(ff2_w, WF2, 1572864);
  cvt_outw_k<<<dim3(576), dim3(256), 0, stream>>>(out_w, WOUT);
  cvt_outb_k<<<dim3(5), dim3(256), 0, stream>>>(out_b, BOUT);
  cvt_memb_k<<<dim3(128), dim3(256), 0, stream>>>(encoder_out, MEMB);

  // ---- embedding ----
  embed_k<<<dim3(MTOT / 4), dim3(256), 0, stream>>>(emb, point_out, pos, tgt, X, XB);

  // ---- cross-attention vectors, all 6 layers (independent of x) ----
  // tmp[l] = mem @ Wv[l].T + bv[l]
  gemm_bt<<<dim3(4, 2, 6), dim3(256), 0, stream>>>(
      MEMB, WCAV, ca_inb + 1024, nullptr, nullptr, CATMP,
      256, 512, 512, 512, 512, 0,
      0L, 262144L, 1536L, 131072L);
  // cav[l] = tmp[l] @ Wo[l].T + ob[l]
  gemm_bt<<<dim3(4, 2, 6), dim3(256), 0, stream>>>(
      CATMP, WCO, ca_outb, nullptr, CAV, nullptr,
      256, 512, 512, 512, 512, 0,
      131072L, 262144L, 512L, 131072L);

  for (int l = 0; l < 6; ++l) {
    // QKV
    gemm_bt<<<dim3(12, 122, 1), dim3(256), 0, stream>>>(
        XB, WSA + (long)l * 786432, sa_inb + l * 1536, nullptr, nullptr, BIG,
        MTOT, 1536, 512, 1536, 1536, 0, 0L, 0L, 0L, 0L);
    // fused attention
    attn_k<<<dim3(2048), dim3(256), 0, stream>>>(BIG, tgt, ATT);
    // out-proj + residual into X
    gemm_bt<<<dim3(4, 122, 1), dim3(256), 0, stream>>>(
        ATT, WSO + (long)l * 262144, sa_outb + l * 512, X, X, nullptr,
        MTOT, 512, 512, 512, 512, 0, 0L, 0L, 0L, 0L);
    // LN1 (in place)
    ln_k<<<dim3(MTOT / 4), dim3(256), 0, stream>>>(X, nullptr, ln1_s + l * 512, ln1_b + l * 512, X, XB);
    // LN2 with cross-attn broadcast add
    ln_k<<<dim3(MTOT / 4), dim3(256), 0, stream>>>(X, CAV + (long)l * 131072, ln2_s + l * 512, ln2_b + l * 512, X, XB);
    // FF1 + ReLU -> h1 (bf16)
    gemm_bt<<<dim3(16, 122, 1), dim3(256), 0, stream>>>(
        XB, WF1 + (long)l * 1048576, ff1_b + l * 2048, nullptr, nullptr, BIG,
        MTOT, 2048, 512, 2048, 2048, 1, 0L, 0L, 0L, 0L);
    // FF2 + residual into X
    gemm_bt<<<dim3(4, 122, 1), dim3(256), 0, stream>>>(
        BIG, WF2 + (long)l * 1048576, ff2_b + l * 512, X, X, nullptr,
        MTOT, 512, 2048, 512, 512, 0, 0L, 0L, 0L, 0L);
    // LN3
    ln_k<<<dim3(MTOT / 4), dim3(256), 0, stream>>>(X, nullptr, ln3_s + l * 512, ln3_b + l * 512, X, XB);
  }

  // ---- final logits: [15616][1027] f32 ----
  gemm_bt<<<dim3(9, 122, 1), dim3(256), 0, stream>>>(
      XB, WOUT, BOUT, nullptr, (float*)d_out, nullptr,
      MTOT, 1152, 512, 1027, 1027, 0, 0L, 0L, 0L, 0L);
}

// Round 2
// 1550.424 us; speedup vs baseline: 1.1099x; 1.1099x over previous
//
#include <hip/hip_runtime.h>
#include <stdint.h>
#include <stddef.h>

typedef unsigned short u16;
typedef float f4 __attribute__((ext_vector_type(4)));
typedef float f32x4 __attribute__((ext_vector_type(4)));
typedef short bf16x8 __attribute__((ext_vector_type(8)));
typedef u16 u16x4 __attribute__((ext_vector_type(4)));
typedef int i4v __attribute__((ext_vector_type(4)));

#define PAD_TOK 1026
#define LQ 61
#define NBATCH 256
#define MTOT (NBATCH * LQ)   // 15616 = 122*128 = 244*64

__device__ __forceinline__ u16 f2b(float f) {
  uint32_t x = __float_as_uint(f);
  x += 0x7fff + ((x >> 16) & 1);   // RNE
  return (u16)(x >> 16);
}

// ---------------------------------------------------------------------------
// Generic bf16 B^T GEMM: C[m][n] = sum_k A[m][k] * W[n][k] + bias[n] (+resid)
// BM x 128 tile (BM=128 or 64), BK=64, 4 waves, global_load_lds(16B) with
// XOR-swizzled source (linear LDS dest, swizzled ds_read: rule-21).
// BM=64 halves LDS (24KB) and doubles grid for the skinny N=512 GEMMs.
// ---------------------------------------------------------------------------
template<int BM>
__global__ __launch_bounds__(256) void gemm_bt(
    const u16* __restrict__ A, const u16* __restrict__ W,
    const float* __restrict__ bias, const float* __restrict__ resid,
    float* __restrict__ Cf, u16* __restrict__ Cb,
    int M, int N, int K, int Nreal, int ldc, int relu,
    long aZ, long wZ, long bZ, long cZ)
{
  constexpr int MI = BM / 32;            // M-frags per wave (4 or 2)
  const int z = blockIdx.z;
  A += z * aZ; W += z * wZ; bias += z * bZ;
  if (Cf) Cf += z * cZ;
  if (Cb) Cb += z * cZ;

  __shared__ u16 As[BM * 64];
  __shared__ u16 Bs[128 * 64];

  const int tid = threadIdx.x;
  const int wid = tid >> 6, lane = tid & 63;
  const int wr = wid >> 1, wc = wid & 1;
  const long m0 = (long)blockIdx.y * BM;
  const long n0 = (long)blockIdx.x * 128;

  const int lr = lane >> 3;              // row-in-8 for staging
  const int lc = lane & 7;               // 16B chunk
  const int scol = ((lc ^ lr) << 3);     // pre-swizzled source col (elems)

  f32x4 acc[MI][4];
#pragma unroll
  for (int i = 0; i < MI; ++i)
#pragma unroll
    for (int j = 0; j < 4; ++j) acc[i][j] = (f32x4){0.f, 0.f, 0.f, 0.f};

  const u16* Abase = A + m0 * K;
  const u16* Wbase = W + n0 * K;
  const int r = lane & 15, kg = lane >> 4;

  for (int kt = 0; kt < K; kt += 64) {
#pragma unroll
    for (int c = 0; c < BM / 32; ++c) {  // A: BM rows total, 8 rows/wave-call
      const int row = wid * (BM / 4) + c * 8;
      __builtin_amdgcn_global_load_lds(
          (const __attribute__((address_space(1))) void*)(Abase + (long)(row + lr) * K + kt + scol),
          (__attribute__((address_space(3))) void*)&As[row * 64], 16, 0, 0);
    }
#pragma unroll
    for (int c = 0; c < 4; ++c) {        // B: 128 rows
      const int row = wid * 32 + c * 8;
      __builtin_amdgcn_global_load_lds(
          (const __attribute__((address_space(1))) void*)(Wbase + (long)(row + lr) * K + kt + scol),
          (__attribute__((address_space(3))) void*)&Bs[row * 64], 16, 0, 0);
    }
    __syncthreads();

#pragma unroll
    for (int ks = 0; ks < 64; ks += 32) {
      bf16x8 a[MI], b[4];
#pragma unroll
      for (int mi = 0; mi < MI; ++mi) {
        const int row = wr * (BM / 2) + mi * 16 + r;
        const int chunk = ((ks >> 3) + kg) ^ (row & 7);
        a[mi] = *(const bf16x8*)&As[row * 64 + chunk * 8];
      }
#pragma unroll
      for (int ni = 0; ni < 4; ++ni) {
        const int row = wc * 64 + ni * 16 + r;
        const int chunk = ((ks >> 3) + kg) ^ (row & 7);
        b[ni] = *(const bf16x8*)&Bs[row * 64 + chunk * 8];
      }
#pragma unroll
      for (int mi = 0; mi < MI; ++mi)
#pragma unroll
        for (int ni = 0; ni < 4; ++ni)
          acc[mi][ni] = __builtin_amdgcn_mfma_f32_16x16x32_bf16(a[mi], b[ni], acc[mi][ni], 0, 0, 0);
    }
    __syncthreads();
  }

  // epilogue: C row = (lane>>4)*4+j, col = lane&15  (verified m89 layout)
  const int cr = (lane >> 4) * 4;
  const int cc = lane & 15;
#pragma unroll
  for (int ni = 0; ni < 4; ++ni) {
    const int n = (int)n0 + wc * 64 + ni * 16 + cc;
    if (n >= Nreal) continue;
    const float bv = bias[n];
#pragma unroll
    for (int mi = 0; mi < MI; ++mi) {
#pragma unroll
      for (int j = 0; j < 4; ++j) {
        const long m = m0 + wr * (BM / 2) + mi * 16 + cr + j;
        float v = acc[mi][ni][j] + bv;
        if (resid) v += resid[m * 512 + n];
        if (relu) v = fmaxf(v, 0.f);
        if (Cf) Cf[m * ldc + n] = v;
        if (Cb) Cb[m * (long)N + n] = f2b(v);
      }
    }
  }
}

// ---------------------------------------------------------------------------
// Fused self-attention: one block per (batch, head). 61 queries/keys padded
// to 64. MFMA for QK^T and PV; softmax via LDS + 4-lane shfl groups.
// ---------------------------------------------------------------------------
__global__ __launch_bounds__(256) void attn_k(const u16* __restrict__ qkv,
                                              const int* __restrict__ tgt,
                                              u16* __restrict__ outp)
{
  __shared__ u16 Qs[64 * 72];   // also reused as P (bf16)
  __shared__ u16 Ks[64 * 72];
  __shared__ u16 Vt[64 * 72];   // V^T: rows d, cols k
  __shared__ float S[64 * 65];
  __shared__ int stok[64];

  const int bid = blockIdx.x;
  const int b = bid >> 3, h = bid & 7;
  const int tid = threadIdx.x;
  const int tr = tid >> 2, seg = tid & 3;

  if (tid < 64) stok[tid] = (tid < 61) ? tgt[b * 62 + tid] : -1;

  const long rowbase = ((long)(b * LQ + tr)) * 1536 + h * 64;
  if (tr < LQ) {
    const i4v* qsrc = (const i4v*)(qkv + rowbase + seg * 16);
    i4v q0 = qsrc[0], q1 = qsrc[1];
    *(i4v*)&Qs[tr * 72 + seg * 16] = q0;
    *(i4v*)&Qs[tr * 72 + seg * 16 + 8] = q1;
    const i4v* ksrc = (const i4v*)(qkv + rowbase + 512 + seg * 16);
    i4v k0 = ksrc[0], k1 = ksrc[1];
    *(i4v*)&Ks[tr * 72 + seg * 16] = k0;
    *(i4v*)&Ks[tr * 72 + seg * 16 + 8] = k1;
    const u16* vsrc = qkv + rowbase + 1024 + seg * 16;
#pragma unroll
    for (int i = 0; i < 16; ++i) Vt[(seg * 16 + i) * 72 + tr] = vsrc[i];
  } else {
    i4v zz = {0, 0, 0, 0};
    *(i4v*)&Qs[tr * 72 + seg * 16] = zz;
    *(i4v*)&Qs[tr * 72 + seg * 16 + 8] = zz;
    *(i4v*)&Ks[tr * 72 + seg * 16] = zz;
    *(i4v*)&Ks[tr * 72 + seg * 16 + 8] = zz;
#pragma unroll
    for (int i = 0; i < 16; ++i) Vt[(seg * 16 + i) * 72 + tr] = 0;
  }
  __syncthreads();

  const int lane = tid & 63, w = tid >> 6;
  const int r = lane & 15, kg = lane >> 4;

  {   // QK^T: wave w computes S rows [16w,16w+16)
    f32x4 s[4];
#pragma unroll
    for (int ni = 0; ni < 4; ++ni) s[ni] = (f32x4){0.f, 0.f, 0.f, 0.f};
    bf16x8 a0 = *(const bf16x8*)&Qs[(w * 16 + r) * 72 + kg * 8];
    bf16x8 a1 = *(const bf16x8*)&Qs[(w * 16 + r) * 72 + 32 + kg * 8];
#pragma unroll
    for (int ni = 0; ni < 4; ++ni) {
      bf16x8 b0 = *(const bf16x8*)&Ks[(ni * 16 + r) * 72 + kg * 8];
      bf16x8 b1 = *(const bf16x8*)&Ks[(ni * 16 + r) * 72 + 32 + kg * 8];
      s[ni] = __builtin_amdgcn_mfma_f32_16x16x32_bf16(a0, b0, s[ni], 0, 0, 0);
      s[ni] = __builtin_amdgcn_mfma_f32_16x16x32_bf16(a1, b1, s[ni], 0, 0, 0);
    }
#pragma unroll
    for (int ni = 0; ni < 4; ++ni)
#pragma unroll
      for (int j = 0; j < 4; ++j)
        S[(w * 16 + kg * 4 + j) * 65 + ni * 16 + r] = s[ni][j];
  }
  __syncthreads();

  {   // masked softmax, 4 lanes per row, 16 cols each; P -> Qs (bf16)
    const int row = tid >> 2, g = tid & 3;
    float vals[16];
    float mx = -3e38f;
#pragma unroll
    for (int i = 0; i < 16; ++i) {
      const int k = g * 16 + i;
      float v = S[row * 65 + k] * 0.125f;
      const bool ok = (k <= row) && (k < LQ) && (stok[k] != PAD_TOK);
      v = ok ? v : -1e30f;
      vals[i] = v;
      mx = fmaxf(mx, v);
    }
    mx = fmaxf(mx, __shfl_xor(mx, 1));
    mx = fmaxf(mx, __shfl_xor(mx, 2));
    float sum = 0.f;
#pragma unroll
    for (int i = 0; i < 16; ++i) { float e = __expf(vals[i] - mx); vals[i] = e; sum += e; }
    sum += __shfl_xor(sum, 1);
    sum += __shfl_xor(sum, 2);
    const float inv = 1.f / sum;
#pragma unroll
    for (int i = 0; i < 16; ++i) Qs[row * 72 + g * 16 + i] = f2b(vals[i] * inv);
  }
  __syncthreads();

  {   // PV: O rows [16w,16w+16), cols d = ni*16+r
    f32x4 o[4];
#pragma unroll
    for (int ni = 0; ni < 4; ++ni) o[ni] = (f32x4){0.f, 0.f, 0.f, 0.f};
    bf16x8 a0 = *(const bf16x8*)&Qs[(w * 16 + r) * 72 + kg * 8];
    bf16x8 a1 = *(const bf16x8*)&Qs[(w * 16 + r) * 72 + 32 + kg * 8];
#pragma unroll
    for (int ni = 0; ni < 4; ++ni) {
      bf16x8 b0 = *(const bf16x8*)&Vt[(ni * 16 + r) * 72 + kg * 8];
      bf16x8 b1 = *(const bf16x8*)&Vt[(ni * 16 + r) * 72 + 32 + kg * 8];
      o[ni] = __builtin_amdgcn_mfma_f32_16x16x32_bf16(a0, b0, o[ni], 0, 0, 0);
      o[ni] = __builtin_amdgcn_mfma_f32_16x16x32_bf16(a1, b1, o[ni], 0, 0, 0);
    }
#pragma unroll
    for (int ni = 0; ni < 4; ++ni)
#pragma unroll
      for (int j = 0; j < 4; ++j) {
        const int q = w * 16 + kg * 4 + j;
        if (q < LQ)
          outp[((long)(b * LQ + q)) * 512 + h * 64 + ni * 16 + r] = f2b(o[ni][j]);
      }
  }
}

__device__ __forceinline__ void ln_row(f4& v0, f4& v1,
                                       const float* __restrict__ sw,
                                       const float* __restrict__ bw, int d0) {
  float s1 = v0[0] + v0[1] + v0[2] + v0[3] + v1[0] + v1[1] + v1[2] + v1[3];
  float s2 = v0[0]*v0[0] + v0[1]*v0[1] + v0[2]*v0[2] + v0[3]*v0[3]
           + v1[0]*v1[0] + v1[1]*v1[1] + v1[2]*v1[2] + v1[3]*v1[3];
#pragma unroll
  for (int off = 1; off < 64; off <<= 1) {
    s1 += __shfl_xor(s1, off);
    s2 += __shfl_xor(s2, off);
  }
  const float mean = s1 * (1.f / 512.f);
  const float var = s2 * (1.f / 512.f) - mean * mean;
  const float rstd = rsqrtf(var + 1e-5f);
  const f4* sp = (const f4*)(sw + d0);
  const f4* bp = (const f4*)(bw + d0);
  f4 ss0 = sp[0], ss1 = sp[1], bb0 = bp[0], bb1 = bp[1];
#pragma unroll
  for (int i = 0; i < 4; ++i) {
    v0[i] = (v0[i] - mean) * rstd * ss0[i] + bb0[i];
    v1[i] = (v1[i] - mean) * rstd * ss1[i] + bb1[i];
  }
}

// LayerNorm over D=512: one wave per row. Writes f32 x and bf16 mirror.
__global__ __launch_bounds__(256) void ln_k(const float* __restrict__ src,
                                            const float* __restrict__ sw,
                                            const float* __restrict__ bw,
                                            float* __restrict__ X,
                                            u16* __restrict__ XB)
{
  const int m = blockIdx.x * 4 + (threadIdx.x >> 6);
  const int lane = threadIdx.x & 63;
  const int d0 = lane * 8;
  const f4* p = (const f4*)(src + (long)m * 512 + d0);
  f4 v0 = p[0], v1 = p[1];
  ln_row(v0, v1, sw, bw, d0);
  f4* xo = (f4*)(X + (long)m * 512 + d0);
  xo[0] = v0; xo[1] = v1;
  u16x4* xb = (u16x4*)(XB + (long)m * 512 + d0);
  xb[0] = (u16x4){f2b(v0[0]), f2b(v0[1]), f2b(v0[2]), f2b(v0[3])};
  xb[1] = (u16x4){f2b(v1[0]), f2b(v1[1]), f2b(v1[2]), f2b(v1[3])};
}

// Fused LN1 -> +cav (per-batch broadcast) -> LN2, single pass over X.
__global__ __launch_bounds__(256) void ln12_k(const float* __restrict__ src,
                                              const float* __restrict__ cav,
                                              const float* __restrict__ s1w,
                                              const float* __restrict__ b1w,
                                              const float* __restrict__ s2w,
                                              const float* __restrict__ b2w,
                                              float* __restrict__ X,
                                              u16* __restrict__ XB)
{
  const int m = blockIdx.x * 4 + (threadIdx.x >> 6);
  const int lane = threadIdx.x & 63;
  const int d0 = lane * 8;
  const f4* p = (const f4*)(src + (long)m * 512 + d0);
  f4 v0 = p[0], v1 = p[1];
  ln_row(v0, v1, s1w, b1w, d0);
  const int b = m / LQ;
  const f4* q = (const f4*)(cav + (long)b * 512 + d0);
  v0 += q[0]; v1 += q[1];
  ln_row(v0, v1, s2w, b2w, d0);
  f4* xo = (f4*)(X + (long)m * 512 + d0);
  xo[0] = v0; xo[1] = v1;
  u16x4* xb = (u16x4*)(XB + (long)m * 512 + d0);
  xb[0] = (u16x4){f2b(v0[0]), f2b(v0[1]), f2b(v0[2]), f2b(v0[3])};
  xb[1] = (u16x4){f2b(v1[0]), f2b(v1[1]), f2b(v1[2]), f2b(v1[3])};
}

// Embedding: x[m] = emb[tok] + point_out[b] + pos_embed[t]
__global__ __launch_bounds__(256) void embed_k(const float* __restrict__ emb,
                                               const float* __restrict__ pout,
                                               const float* __restrict__ pos,
                                               const int* __restrict__ tgt,
                                               float* __restrict__ X,
                                               u16* __restrict__ XB)
{
  const int m = blockIdx.x * 4 + (threadIdx.x >> 6);
  const int lane = threadIdx.x & 63;
  const int b = m / LQ, t = m % LQ;
  const int tok = tgt[b * 62 + t];
  const int d0 = lane * 8;
  const f4* e = (const f4*)(emb + (long)tok * 512 + d0);
  const f4* p = (const f4*)(pout + (long)b * 512 + d0);
  const f4* q = (const f4*)(pos + (long)t * 512 + d0);
  f4 v0 = e[0] + p[0] + q[0];
  f4 v1 = e[1] + p[1] + q[1];
  f4* xo = (f4*)(X + (long)m * 512 + d0);
  xo[0] = v0; xo[1] = v1;
  u16x4* xb = (u16x4*)(XB + (long)m * 512 + d0);
  xb[0] = (u16x4){f2b(v0[0]), f2b(v0[1]), f2b(v0[2]), f2b(v0[3])};
  xb[1] = (u16x4){f2b(v1[0]), f2b(v1[1]), f2b(v1[2]), f2b(v1[3])};
}

// f32 -> bf16 converters
__global__ void cvt_bf16_k(const float* __restrict__ src, u16* __restrict__ dst, int n4) {
  const int i = blockIdx.x * 256 + threadIdx.x;
  if (i >= n4) return;
  f4 v = ((const f4*)src)[i];
  ((u16x4*)dst)[i] = (u16x4){f2b(v[0]), f2b(v[1]), f2b(v[2]), f2b(v[3])};
}

__global__ void cvt_ca_v_k(const float* __restrict__ ca_inw, u16* __restrict__ dst) {
  const int i = blockIdx.x * 256 + threadIdx.x;
  if (i >= 393216) return;                  // 6*512*512/4
  const int l = i >> 16, rem = i & 65535;
  f4 v = ((const f4*)ca_inw)[l * 196608 + 131072 + rem];
  ((u16x4*)dst)[i] = (u16x4){f2b(v[0]), f2b(v[1]), f2b(v[2]), f2b(v[3])};
}

__global__ void cvt_outw_k(const float* __restrict__ out_w, u16* __restrict__ dst) {
  const int i = blockIdx.x * 256 + threadIdx.x;
  if (i >= 147456) return;                  // 1152*512/4
  const int row = (i * 4) >> 9;
  u16x4 o = {0, 0, 0, 0};
  if (row < 1027) {
    f4 v = ((const f4*)out_w)[i];
    o = (u16x4){f2b(v[0]), f2b(v[1]), f2b(v[2]), f2b(v[3])};
  }
  ((u16x4*)dst)[i] = o;
}

__global__ void cvt_outb_k(const float* __restrict__ out_b, float* __restrict__ dst) {
  const int i = blockIdx.x * 256 + threadIdx.x;
  if (i >= 1152) return;
  dst[i] = (i < 1027) ? out_b[i] : 0.f;
}

__global__ void cvt_memb_k(const float* __restrict__ enc, u16* __restrict__ dst) {
  const int i = blockIdx.x * 256 + threadIdx.x;
  if (i >= 32768) return;                   // 256*512/4
  const int b = (i * 4) >> 9, d = (i * 4) & 511;
  f4 v = ((const f4*)enc)[(b * 8192 + d) >> 2];
  ((u16x4*)dst)[i] = (u16x4){f2b(v[0]), f2b(v[1]), f2b(v[2]), f2b(v[3])};
}

// ---------------------------------------------------------------------------
// Workspace layout (bytes)
// ---------------------------------------------------------------------------
static constexpr size_t XB_OFF    = 0;                       // bf16 [15616][512]
static constexpr size_t X_OFF     = 15990784;                // f32  [15616][512]
static constexpr size_t BIG_OFF   = 47972352;                // bf16 qkv[15616][1536] / h1[15616][2048]
static constexpr size_t ATT_OFF   = 111935488;               // bf16 [15616][512]
static constexpr size_t WSA_OFF   = 127926272;               // bf16 [6][1536][512]
static constexpr size_t WSO_OFF   = 137363456;               // bf16 [6][512][512]
static constexpr size_t WCAV_OFF  = 140509184;               // bf16 [6][512][512]
static constexpr size_t WCO_OFF   = 143654912;               // bf16 [6][512][512]
static constexpr size_t WF1_OFF   = 146800640;               // bf16 [6][2048][512]
static constexpr size_t WF2_OFF   = 159383552;               // bf16 [6][512][2048]
static constexpr size_t WOUT_OFF  = 171966464;               // bf16 [1152][512]
static constexpr size_t BOUT_OFF  = 173146112;               // f32  [1152]
static constexpr size_t MEMB_OFF  = 173150720;               // bf16 [256][512]
static constexpr size_t CATMP_OFF = 173412864;               // bf16 [6][256][512]
static constexpr size_t CAV_OFF   = 174985728;               // f32  [6][256][512]

extern "C" void kernel_launch(void* const* d_in, const int* in_sizes, int n_in,
                              void* d_out, int out_size, void* d_ws, size_t ws_size,
                              hipStream_t stream) {
  (void)in_sizes; (void)n_in; (void)out_size; (void)ws_size;
  const float* encoder_out = (const float*)d_in[0];
  const float* point_out   = (const float*)d_in[1];
  const float* emb         = (const float*)d_in[2];
  const float* pos         = (const float*)d_in[3];
  const float* sa_inw      = (const float*)d_in[4];
  const float* sa_inb      = (const float*)d_in[5];
  const float* sa_outw     = (const float*)d_in[6];
  const float* sa_outb     = (const float*)d_in[7];
  const float* ca_inw      = (const float*)d_in[8];
  const float* ca_inb      = (const float*)d_in[9];
  const float* ca_outw     = (const float*)d_in[10];
  const float* ca_outb     = (const float*)d_in[11];
  const float* ln1_s       = (const float*)d_in[12];
  const float* ln1_b       = (const float*)d_in[13];
  const float* ln2_s       = (const float*)d_in[14];
  const float* ln2_b       = (const float*)d_in[15];
  const float* ln3_s       = (const float*)d_in[16];
  const float* ln3_b       = (const float*)d_in[17];
  const float* ff1_w       = (const float*)d_in[18];
  const float* ff1_b       = (const float*)d_in[19];
  const float* ff2_w       = (const float*)d_in[20];
  const float* ff2_b       = (const float*)d_in[21];
  const float* out_w       = (const float*)d_in[22];
  const float* out_b       = (const float*)d_in[23];
  const int*   tgt         = (const int*)d_in[24];

  char* ws = (char*)d_ws;
  u16*   XB    = (u16*)(ws + XB_OFF);
  float* X     = (float*)(ws + X_OFF);
  u16*   BIG   = (u16*)(ws + BIG_OFF);
  u16*   ATT   = (u16*)(ws + ATT_OFF);
  u16*   WSA   = (u16*)(ws + WSA_OFF);
  u16*   WSO   = (u16*)(ws + WSO_OFF);
  u16*   WCAV  = (u16*)(ws + WCAV_OFF);
  u16*   WCO   = (u16*)(ws + WCO_OFF);
  u16*   WF1   = (u16*)(ws + WF1_OFF);
  u16*   WF2   = (u16*)(ws + WF2_OFF);
  u16*   WOUT  = (u16*)(ws + WOUT_OFF);
  float* BOUT  = (float*)(ws + BOUT_OFF);
  u16*   MEMB  = (u16*)(ws + MEMB_OFF);
  u16*   CATMP = (u16*)(ws + CATMP_OFF);
  float* CAV   = (float*)(ws + CAV_OFF);

  // ---- weight conversion ----
  cvt_bf16_k<<<dim3(4608), dim3(256), 0, stream>>>(sa_inw, WSA, 1179648);
  cvt_bf16_k<<<dim3(1536), dim3(256), 0, stream>>>(sa_outw, WSO, 393216);
  cvt_ca_v_k<<<dim3(1536), dim3(256), 0, stream>>>(ca_inw, WCAV);
  cvt_bf16_k<<<dim3(1536), dim3(256), 0, stream>>>(ca_outw, WCO, 393216);
  cvt_bf16_k<<<dim3(6144), dim3(256), 0, stream>>>(ff1_w, WF1, 1572864);
  cvt_bf16_k<<<dim3(6144), dim3(256), 0, stream>>>(ff2_w, WF2, 1572864);
  cvt_outw_k<<<dim3(576), dim3(256), 0, stream>>>(out_w, WOUT);
  cvt_outb_k<<<dim3(5), dim3(256), 0, stream>>>(out_b, BOUT);
  cvt_memb_k<<<dim3(128), dim3(256), 0, stream>>>(encoder_out, MEMB);

  // ---- embedding ----
  embed_k<<<dim3(MTOT / 4), dim3(256), 0, stream>>>(emb, point_out, pos, tgt, X, XB);

  // ---- cross-attention vectors, all 6 layers (independent of x) ----
  gemm_bt<64><<<dim3(4, 4, 6), dim3(256), 0, stream>>>(
      MEMB, WCAV, ca_inb + 1024, nullptr, nullptr, CATMP,
      256, 512, 512, 512, 512, 0,
      0L, 262144L, 1536L, 131072L);
  gemm_bt<64><<<dim3(4, 4, 6), dim3(256), 0, stream>>>(
      CATMP, WCO, ca_outb, nullptr, CAV, nullptr,
      256, 512, 512, 512, 512, 0,
      131072L, 262144L, 512L, 131072L);

  for (int l = 0; l < 6; ++l) {
    // QKV
    gemm_bt<128><<<dim3(12, 122, 1), dim3(256), 0, stream>>>(
        XB, WSA + (long)l * 786432, sa_inb + l * 1536, nullptr, nullptr, BIG,
        MTOT, 1536, 512, 1536, 1536, 0, 0L, 0L, 0L, 0L);
    // fused attention
    attn_k<<<dim3(2048), dim3(256), 0, stream>>>(BIG, tgt, ATT);
    // out-proj + residual into X (BM=64: 976 blocks)
    gemm_bt<64><<<dim3(4, 244, 1), dim3(256), 0, stream>>>(
        ATT, WSO + (long)l * 262144, sa_outb + l * 512, X, X, nullptr,
        MTOT, 512, 512, 512, 512, 0, 0L, 0L, 0L, 0L);
    // fused LN1 + cross-attn add + LN2
    ln12_k<<<dim3(MTOT / 4), dim3(256), 0, stream>>>(
        X, CAV + (long)l * 131072,
        ln1_s + l * 512, ln1_b + l * 512, ln2_s + l * 512, ln2_b + l * 512,
        X, XB);
    // FF1 + ReLU -> h1 (bf16)
    gemm_bt<128><<<dim3(16, 122, 1), dim3(256), 0, stream>>>(
        XB, WF1 + (long)l * 1048576, ff1_b + l * 2048, nullptr, nullptr, BIG,
        MTOT, 2048, 512, 2048, 2048, 1, 0L, 0L, 0L, 0L);
    // FF2 + residual into X (BM=64: 976 blocks)
    gemm_bt<64><<<dim3(4, 244, 1), dim3(256), 0, stream>>>(
        BIG, WF2 + (long)l * 1048576, ff2_b + l * 512, X, X, nullptr,
        MTOT, 512, 2048, 512, 512, 0, 0L, 0L, 0L, 0L);
    // LN3
    ln_k<<<dim3(MTOT / 4), dim3(256), 0, stream>>>(X, ln3_s + l * 512, ln3_b + l * 512, X, XB);
  }

  // ---- final logits: [15616][1027] f32 ----
  gemm_bt<128><<<dim3(9, 122, 1), dim3(256), 0, stream>>>(
      XB, WOUT, BOUT, nullptr, (float*)d_out, nullptr,
      MTOT, 1152, 512, 1027, 1027, 0, 0L, 0L, 0L, 0L);
}

// Round 3
// 1216.021 us; speedup vs baseline: 1.4151x; 1.2750x over previous
//
#include <hip/hip_runtime.h>
#include <stdint.h>
#include <stddef.h>

typedef unsigned short u16;
typedef float f4 __attribute__((ext_vector_type(4)));
typedef float f32x4 __attribute__((ext_vector_type(4)));
typedef short bf16x8 __attribute__((ext_vector_type(8)));
typedef u16 u16x4 __attribute__((ext_vector_type(4)));
typedef int i4v __attribute__((ext_vector_type(4)));

#define PAD_TOK 1026
#define LQ 61
#define NBATCH 256
#define MTOT (NBATCH * LQ)   // 15616 = 122*128 = 244*64

__device__ __forceinline__ u16 f2b(float f) {
  uint32_t x = __float_as_uint(f);
  x += 0x7fff + ((x >> 16) & 1);   // RNE
  return (u16)(x >> 16);
}
__device__ __forceinline__ float b2f(u16 u) {
  return __uint_as_float(((uint32_t)u) << 16);
}

// ---------------------------------------------------------------------------
// bf16 B^T GEMM: C[m][n] = sum_k A[m][k]*W[n][k] + bias[n], optional relu.
// BM x 128 tile, BK=64, 4 waves, global_load_lds(16B), XOR-swizzled LDS reads.
// bf16 output goes through an LDS bounce (reuse As/Bs) for coalesced 16B
// stores (fixes 1.6x write amplification of the 32B-segment scalar stores).
// Bijective XCD swizzle (m204) for L2 locality.
// ---------------------------------------------------------------------------
template<int BM>
__global__ __launch_bounds__(256) void gemm_bt(
    const u16* __restrict__ A, const u16* __restrict__ W,
    const float* __restrict__ bias,
    float* __restrict__ Cf, u16* __restrict__ Cb,
    int M, int N, int K, int Nreal, int ldc, int relu,
    long aZ, long wZ, long bZ, long cZ)
{
  constexpr int MI = BM / 32;            // M-frags per wave (4 or 2)
  const int z = blockIdx.z;
  A += z * aZ; W += z * wZ; bias += z * bZ;
  if (Cf) Cf += z * cZ;
  if (Cb) Cb += z * cZ;

  __shared__ u16 As[BM * 64];
  __shared__ u16 Bs[128 * 64];

  // --- bijective XCD swizzle (m204): each XCD gets a contiguous chunk ---
  const int gx = gridDim.x;
  const int nwg = gx * gridDim.y;
  const int orig = blockIdx.y * gx + blockIdx.x;
  const int q8 = nwg >> 3, r8 = nwg & 7;
  const int xcd = orig & 7, off = orig >> 3;
  const int nid = (xcd < r8 ? xcd * (q8 + 1) : r8 * (q8 + 1) + (xcd - r8) * q8) + off;
  const int bx = nid % gx, by = nid / gx;

  const int tid = threadIdx.x;
  const int wid = tid >> 6, lane = tid & 63;
  const int wr = wid >> 1, wc = wid & 1;
  const long m0 = (long)by * BM;
  const long n0 = (long)bx * 128;

  const int lr = lane >> 3;              // row-in-8 for staging
  const int lc = lane & 7;               // 16B chunk
  const int scol = ((lc ^ lr) << 3);     // pre-swizzled source col (elems)

  f32x4 acc[MI][4];
#pragma unroll
  for (int i = 0; i < MI; ++i)
#pragma unroll
    for (int j = 0; j < 4; ++j) acc[i][j] = (f32x4){0.f, 0.f, 0.f, 0.f};

  const u16* Abase = A + m0 * K;
  const u16* Wbase = W + n0 * K;
  const int r = lane & 15, kg = lane >> 4;

  for (int kt = 0; kt < K; kt += 64) {
#pragma unroll
    for (int c = 0; c < BM / 32; ++c) {  // A: BM rows total
      const int row = wid * (BM / 4) + c * 8;
      __builtin_amdgcn_global_load_lds(
          (const __attribute__((address_space(1))) void*)(Abase + (long)(row + lr) * K + kt + scol),
          (__attribute__((address_space(3))) void*)&As[row * 64], 16, 0, 0);
    }
#pragma unroll
    for (int c = 0; c < 4; ++c) {        // B: 128 rows
      const int row = wid * 32 + c * 8;
      __builtin_amdgcn_global_load_lds(
          (const __attribute__((address_space(1))) void*)(Wbase + (long)(row + lr) * K + kt + scol),
          (__attribute__((address_space(3))) void*)&Bs[row * 64], 16, 0, 0);
    }
    __syncthreads();

#pragma unroll
    for (int ks = 0; ks < 64; ks += 32) {
      bf16x8 a[MI], b[4];
#pragma unroll
      for (int mi = 0; mi < MI; ++mi) {
        const int row = wr * (BM / 2) + mi * 16 + r;
        const int chunk = ((ks >> 3) + kg) ^ (row & 7);
        a[mi] = *(const bf16x8*)&As[row * 64 + chunk * 8];
      }
#pragma unroll
      for (int ni = 0; ni < 4; ++ni) {
        const int row = wc * 64 + ni * 16 + r;
        const int chunk = ((ks >> 3) + kg) ^ (row & 7);
        b[ni] = *(const bf16x8*)&Bs[row * 64 + chunk * 8];
      }
#pragma unroll
      for (int mi = 0; mi < MI; ++mi)
#pragma unroll
        for (int ni = 0; ni < 4; ++ni)
          acc[mi][ni] = __builtin_amdgcn_mfma_f32_16x16x32_bf16(a[mi], b[ni], acc[mi][ni], 0, 0, 0);
    }
    __syncthreads();
  }

  // epilogue: C row = (lane>>4)*4+j, col = lane&15  (verified m89 layout)
  const int cr4 = (lane >> 4) * 4;
  const int cc = lane & 15;

  if (Cb) {
    // ---- LDS bounce for coalesced bf16 stores ----
#pragma unroll
    for (int ni = 0; ni < 4; ++ni) {
      const int coll = wc * 64 + ni * 16 + cc;         // 0..127
      const float bv = bias[(int)n0 + coll];
#pragma unroll
      for (int mi = 0; mi < MI; ++mi) {
#pragma unroll
        for (int j = 0; j < 4; ++j) {
          const int rowl = wr * (BM / 2) + mi * 16 + cr4 + j;
          float v = acc[mi][ni][j] + bv;
          if (relu) v = fmaxf(v, 0.f);
          const int sw = (rowl & 7) << 3;
          u16* half = (coll & 64) ? Bs : As;
          half[rowl * 64 + ((coll & 63) ^ sw)] = f2b(v);
        }
      }
    }
    __syncthreads();
    constexpr int PT = BM / 16;                        // 16B chunks per thread
#pragma unroll
    for (int i = 0; i < PT; ++i) {
      const int t = i * 256 + tid;
      const int row = t >> 4, ch = t & 15;             // 16 chunks of 8 per row
      const int n = (int)n0 + ch * 8;
      if (n < Nreal) {
        const int phys = (ch & 7) ^ (row & 7);
        const u16* half = (ch < 8) ? As : Bs;
        bf16x8 vv = *(const bf16x8*)&half[row * 64 + phys * 8];
        *(bf16x8*)&Cb[(m0 + row) * (long)N + n] = vv;
      }
    }
  } else {
    // ---- f32 scalar path (CAV + final logits) ----
#pragma unroll
    for (int ni = 0; ni < 4; ++ni) {
      const int n = (int)n0 + wc * 64 + ni * 16 + cc;
      if (n >= Nreal) continue;
      const float bv = bias[n];
#pragma unroll
      for (int mi = 0; mi < MI; ++mi) {
#pragma unroll
        for (int j = 0; j < 4; ++j) {
          const long m = m0 + wr * (BM / 2) + mi * 16 + cr4 + j;
          float v = acc[mi][ni][j] + bv;
          if (relu) v = fmaxf(v, 0.f);
          Cf[m * ldc + n] = v;
        }
      }
    }
  }
}

// ---------------------------------------------------------------------------
// Fused self-attention: one block per (batch, head). 61 q/k padded to 64.
// O goes through a swizzled LDS bounce (reuse Ks) for coalesced stores.
// ---------------------------------------------------------------------------
__global__ __launch_bounds__(256) void attn_k(const u16* __restrict__ qkv,
                                              const int* __restrict__ tgt,
                                              u16* __restrict__ outp)
{
  __shared__ u16 Qs[64 * 72];   // also reused as P (bf16)
  __shared__ u16 Ks[64 * 72];   // reused as O bounce
  __shared__ u16 Vt[64 * 72];   // V^T: rows d, cols k
  __shared__ float S[64 * 65];
  __shared__ int stok[64];

  const int bid = blockIdx.x;
  const int b = bid >> 3, h = bid & 7;
  const int tid = threadIdx.x;
  const int tr = tid >> 2, seg = tid & 3;

  if (tid < 64) stok[tid] = (tid < 61) ? tgt[b * 62 + tid] : -1;

  const long rowbase = ((long)(b * LQ + tr)) * 1536 + h * 64;
  if (tr < LQ) {
    const i4v* qsrc = (const i4v*)(qkv + rowbase + seg * 16);
    i4v q0 = qsrc[0], q1 = qsrc[1];
    *(i4v*)&Qs[tr * 72 + seg * 16] = q0;
    *(i4v*)&Qs[tr * 72 + seg * 16 + 8] = q1;
    const i4v* ksrc = (const i4v*)(qkv + rowbase + 512 + seg * 16);
    i4v k0 = ksrc[0], k1 = ksrc[1];
    *(i4v*)&Ks[tr * 72 + seg * 16] = k0;
    *(i4v*)&Ks[tr * 72 + seg * 16 + 8] = k1;
    const u16* vsrc = qkv + rowbase + 1024 + seg * 16;
#pragma unroll
    for (int i = 0; i < 16; ++i) Vt[(seg * 16 + i) * 72 + tr] = vsrc[i];
  } else {
    i4v zz = {0, 0, 0, 0};
    *(i4v*)&Qs[tr * 72 + seg * 16] = zz;
    *(i4v*)&Qs[tr * 72 + seg * 16 + 8] = zz;
    *(i4v*)&Ks[tr * 72 + seg * 16] = zz;
    *(i4v*)&Ks[tr * 72 + seg * 16 + 8] = zz;
#pragma unroll
    for (int i = 0; i < 16; ++i) Vt[(seg * 16 + i) * 72 + tr] = 0;
  }
  __syncthreads();

  const int lane = tid & 63, w = tid >> 6;
  const int r = lane & 15, kg = lane >> 4;

  {   // QK^T: wave w computes S rows [16w,16w+16)
    f32x4 s[4];
#pragma unroll
    for (int ni = 0; ni < 4; ++ni) s[ni] = (f32x4){0.f, 0.f, 0.f, 0.f};
    bf16x8 a0 = *(const bf16x8*)&Qs[(w * 16 + r) * 72 + kg * 8];
    bf16x8 a1 = *(const bf16x8*)&Qs[(w * 16 + r) * 72 + 32 + kg * 8];
#pragma unroll
    for (int ni = 0; ni < 4; ++ni) {
      bf16x8 b0 = *(const bf16x8*)&Ks[(ni * 16 + r) * 72 + kg * 8];
      bf16x8 b1 = *(const bf16x8*)&Ks[(ni * 16 + r) * 72 + 32 + kg * 8];
      s[ni] = __builtin_amdgcn_mfma_f32_16x16x32_bf16(a0, b0, s[ni], 0, 0, 0);
      s[ni] = __builtin_amdgcn_mfma_f32_16x16x32_bf16(a1, b1, s[ni], 0, 0, 0);
    }
#pragma unroll
    for (int ni = 0; ni < 4; ++ni)
#pragma unroll
      for (int j = 0; j < 4; ++j)
        S[(w * 16 + kg * 4 + j) * 65 + ni * 16 + r] = s[ni][j];
  }
  __syncthreads();

  {   // masked softmax, 4 lanes per row, 16 cols each; P -> Qs (bf16)
    const int row = tid >> 2, g = tid & 3;
    float vals[16];
    float mx = -3e38f;
#pragma unroll
    for (int i = 0; i < 16; ++i) {
      const int k = g * 16 + i;
      float v = S[row * 65 + k] * 0.125f;
      const bool ok = (k <= row) && (k < LQ) && (stok[k] != PAD_TOK);
      v = ok ? v : -1e30f;
      vals[i] = v;
      mx = fmaxf(mx, v);
    }
    mx = fmaxf(mx, __shfl_xor(mx, 1));
    mx = fmaxf(mx, __shfl_xor(mx, 2));
    float sum = 0.f;
#pragma unroll
    for (int i = 0; i < 16; ++i) { float e = __expf(vals[i] - mx); vals[i] = e; sum += e; }
    sum += __shfl_xor(sum, 1);
    sum += __shfl_xor(sum, 2);
    const float inv = 1.f / sum;
#pragma unroll
    for (int i = 0; i < 16; ++i) Qs[row * 72 + g * 16 + i] = f2b(vals[i] * inv);
  }
  __syncthreads();

  {   // PV: O rows [16w,16w+16), cols d = ni*16+r; stage into Ks swizzled
    f32x4 o[4];
#pragma unroll
    for (int ni = 0; ni < 4; ++ni) o[ni] = (f32x4){0.f, 0.f, 0.f, 0.f};
    bf16x8 a0 = *(const bf16x8*)&Qs[(w * 16 + r) * 72 + kg * 8];
    bf16x8 a1 = *(const bf16x8*)&Qs[(w * 16 + r) * 72 + 32 + kg * 8];
#pragma unroll
    for (int ni = 0; ni < 4; ++ni) {
      bf16x8 b0 = *(const bf16x8*)&Vt[(ni * 16 + r) * 72 + kg * 8];
      bf16x8 b1 = *(const bf16x8*)&Vt[(ni * 16 + r) * 72 + 32 + kg * 8];
      o[ni] = __builtin_amdgcn_mfma_f32_16x16x32_bf16(a0, b0, o[ni], 0, 0, 0);
      o[ni] = __builtin_amdgcn_mfma_f32_16x16x32_bf16(a1, b1, o[ni], 0, 0, 0);
    }
#pragma unroll
    for (int ni = 0; ni < 4; ++ni)
#pragma unroll
      for (int j = 0; j < 4; ++j) {
        const int qrow = w * 16 + kg * 4 + j;
        const int col = ni * 16 + r;
        Ks[qrow * 64 + (col ^ ((qrow & 7) << 3))] = f2b(o[ni][j]);
      }
  }
  __syncthreads();

  {   // coalesced O store: 4 threads/row, 2x16B each
    const int row = tid >> 2, sub = tid & 3;
    if (row < LQ) {
      const long obase = ((long)(b * LQ + row)) * 512 + h * 64;
#pragma unroll
      for (int i = 0; i < 2; ++i) {
        const int ch = i * 4 + sub;                 // 0..7 (8 chunks of 8)
        const int phys = ch ^ (row & 7);
        bf16x8 vv = *(const bf16x8*)&Ks[row * 64 + phys * 8];
        *(bf16x8*)&outp[obase + ch * 8] = vv;
      }
    }
  }
}

__device__ __forceinline__ void ln_row(f4& v0, f4& v1,
                                       const float* __restrict__ sw,
                                       const float* __restrict__ bw, int d0) {
  float s1 = v0[0] + v0[1] + v0[2] + v0[3] + v1[0] + v1[1] + v1[2] + v1[3];
  float s2 = v0[0]*v0[0] + v0[1]*v0[1] + v0[2]*v0[2] + v0[3]*v0[3]
           + v1[0]*v1[0] + v1[1]*v1[1] + v1[2]*v1[2] + v1[3]*v1[3];
#pragma unroll
  for (int off = 1; off < 64; off <<= 1) {
    s1 += __shfl_xor(s1, off);
    s2 += __shfl_xor(s2, off);
  }
  const float mean = s1 * (1.f / 512.f);
  const float var = s2 * (1.f / 512.f) - mean * mean;
  const float rstd = rsqrtf(var + 1e-5f);
  const f4* sp = (const f4*)(sw + d0);
  const f4* bp = (const f4*)(bw + d0);
  f4 ss0 = sp[0], ss1 = sp[1], bb0 = bp[0], bb1 = bp[1];
#pragma unroll
  for (int i = 0; i < 4; ++i) {
    v0[i] = (v0[i] - mean) * rstd * ss0[i] + bb0[i];
    v1[i] = (v1[i] - mean) * rstd * ss1[i] + bb1[i];
  }
}

// Fused residual + LN (+ CA-broadcast + LN2). All-bf16 spine:
//   CA=true : out = LN2( LN1(p + x) + cav )
//   CA=false: out = LN1(p + x)
template<bool CA>
__global__ __launch_bounds__(256) void lnf_k(const u16* __restrict__ p,
                                             const u16* __restrict__ xr,
                                             const float* __restrict__ cav,
                                             const float* __restrict__ s1,
                                             const float* __restrict__ b1,
                                             const float* __restrict__ s2,
                                             const float* __restrict__ b2,
                                             u16* __restrict__ out)
{
  const int m = blockIdx.x * 4 + (threadIdx.x >> 6);
  const int lane = threadIdx.x & 63;
  const int d0 = lane * 8;
  bf16x8 pv = *(const bf16x8*)(p + (long)m * 512 + d0);
  bf16x8 xv = *(const bf16x8*)(xr + (long)m * 512 + d0);
  f4 v0, v1;
#pragma unroll
  for (int i = 0; i < 4; ++i) {
    v0[i] = b2f((u16)pv[i]) + b2f((u16)xv[i]);
    v1[i] = b2f((u16)pv[4 + i]) + b2f((u16)xv[4 + i]);
  }
  ln_row(v0, v1, s1, b1, d0);
  if constexpr (CA) {
    const int b = m / LQ;
    const f4* qv = (const f4*)(cav + (long)b * 512 + d0);
    v0 += qv[0]; v1 += qv[1];
    ln_row(v0, v1, s2, b2, d0);
  }
  u16x4* ob = (u16x4*)(out + (long)m * 512 + d0);
  ob[0] = (u16x4){f2b(v0[0]), f2b(v0[1]), f2b(v0[2]), f2b(v0[3])};
  ob[1] = (u16x4){f2b(v1[0]), f2b(v1[1]), f2b(v1[2]), f2b(v1[3])};
}

// Embedding: xb[m] = bf16(emb[tok] + point_out[b] + pos_embed[t])
__global__ __launch_bounds__(256) void embed_k(const float* __restrict__ emb,
                                               const float* __restrict__ pout,
                                               const float* __restrict__ pos,
                                               const int* __restrict__ tgt,
                                               u16* __restrict__ XB)
{
  const int m = blockIdx.x * 4 + (threadIdx.x >> 6);
  const int lane = threadIdx.x & 63;
  const int b = m / LQ, t = m % LQ;
  const int tok = tgt[b * 62 + t];
  const int d0 = lane * 8;
  const f4* e = (const f4*)(emb + (long)tok * 512 + d0);
  const f4* p = (const f4*)(pout + (long)b * 512 + d0);
  const f4* q = (const f4*)(pos + (long)t * 512 + d0);
  f4 v0 = e[0] + p[0] + q[0];
  f4 v1 = e[1] + p[1] + q[1];
  u16x4* xb = (u16x4*)(XB + (long)m * 512 + d0);
  xb[0] = (u16x4){f2b(v0[0]), f2b(v0[1]), f2b(v0[2]), f2b(v0[3])};
  xb[1] = (u16x4){f2b(v1[0]), f2b(v1[1]), f2b(v1[2]), f2b(v1[3])};
}

// f32 -> bf16 converters
__global__ void cvt_bf16_k(const float* __restrict__ src, u16* __restrict__ dst, int n4) {
  const int i = blockIdx.x * 256 + threadIdx.x;
  if (i >= n4) return;
  f4 v = ((const f4*)src)[i];
  ((u16x4*)dst)[i] = (u16x4){f2b(v[0]), f2b(v[1]), f2b(v[2]), f2b(v[3])};
}

__global__ void cvt_ca_v_k(const float* __restrict__ ca_inw, u16* __restrict__ dst) {
  const int i = blockIdx.x * 256 + threadIdx.x;
  if (i >= 393216) return;                  // 6*512*512/4
  const int l = i >> 16, rem = i & 65535;
  f4 v = ((const f4*)ca_inw)[l * 196608 + 131072 + rem];
  ((u16x4*)dst)[i] = (u16x4){f2b(v[0]), f2b(v[1]), f2b(v[2]), f2b(v[3])};
}

__global__ void cvt_outw_k(const float* __restrict__ out_w, u16* __restrict__ dst) {
  const int i = blockIdx.x * 256 + threadIdx.x;
  if (i >= 147456) return;                  // 1152*512/4
  const int row = (i * 4) >> 9;
  u16x4 o = {0, 0, 0, 0};
  if (row < 1027) {
    f4 v = ((const f4*)out_w)[i];
    o = (u16x4){f2b(v[0]), f2b(v[1]), f2b(v[2]), f2b(v[3])};
  }
  ((u16x4*)dst)[i] = o;
}

__global__ void cvt_outb_k(const float* __restrict__ out_b, float* __restrict__ dst) {
  const int i = blockIdx.x * 256 + threadIdx.x;
  if (i >= 1152) return;
  dst[i] = (i < 1027) ? out_b[i] : 0.f;
}

__global__ void cvt_memb_k(const float* __restrict__ enc, u16* __restrict__ dst) {
  const int i = blockIdx.x * 256 + threadIdx.x;
  if (i >= 32768) return;                   // 256*512/4
  const int b = (i * 4) >> 9, d = (i * 4) & 511;
  f4 v = ((const f4*)enc)[(b * 8192 + d) >> 2];
  ((u16x4*)dst)[i] = (u16x4){f2b(v[0]), f2b(v[1]), f2b(v[2]), f2b(v[3])};
}

// ---------------------------------------------------------------------------
// Workspace layout (bytes) — all-bf16 activation spine, no f32 X.
// ---------------------------------------------------------------------------
static constexpr size_t XB_OFF    = 0;            // bf16 [15616][512]
static constexpr size_t P_OFF     = 15990784;     // bf16 [15616][512] raw gemm out
static constexpr size_t BIG_OFF   = 31981568;     // bf16 qkv[15616][1536]/h1[15616][2048]
static constexpr size_t ATT_OFF   = 95944704;     // bf16 [15616][512]
static constexpr size_t WSA_OFF   = 111935488;    // bf16 [6][1536][512]
static constexpr size_t WSO_OFF   = 121372672;    // bf16 [6][512][512]
static constexpr size_t WCAV_OFF  = 124518400;    // bf16 [6][512][512]
static constexpr size_t WCO_OFF   = 127664128;    // bf16 [6][512][512]
static constexpr size_t WF1_OFF   = 130809856;    // bf16 [6][2048][512]
static constexpr size_t WF2_OFF   = 143392768;    // bf16 [6][512][2048]
static constexpr size_t WOUT_OFF  = 155975680;    // bf16 [1152][512]
static constexpr size_t BOUT_OFF  = 157155328;    // f32  [1152]
static constexpr size_t MEMB_OFF  = 157159936;    // bf16 [256][512]
static constexpr size_t CATMP_OFF = 157422080;    // bf16 [6][256][512]
static constexpr size_t CAV_OFF   = 158994944;    // f32  [6][256][512]

extern "C" void kernel_launch(void* const* d_in, const int* in_sizes, int n_in,
                              void* d_out, int out_size, void* d_ws, size_t ws_size,
                              hipStream_t stream) {
  (void)in_sizes; (void)n_in; (void)out_size; (void)ws_size;
  const float* encoder_out = (const float*)d_in[0];
  const float* point_out   = (const float*)d_in[1];
  const float* emb         = (const float*)d_in[2];
  const float* pos         = (const float*)d_in[3];
  const float* sa_inw      = (const float*)d_in[4];
  const float* sa_inb      = (const float*)d_in[5];
  const float* sa_outw     = (const float*)d_in[6];
  const float* sa_outb     = (const float*)d_in[7];
  const float* ca_inw      = (const float*)d_in[8];
  const float* ca_inb      = (const float*)d_in[9];
  const float* ca_outw     = (const float*)d_in[10];
  const float* ca_outb     = (const float*)d_in[11];
  const float* ln1_s       = (const float*)d_in[12];
  const float* ln1_b       = (const float*)d_in[13];
  const float* ln2_s       = (const float*)d_in[14];
  const float* ln2_b       = (const float*)d_in[15];
  const float* ln3_s       = (const float*)d_in[16];
  const float* ln3_b       = (const float*)d_in[17];
  const float* ff1_w       = (const float*)d_in[18];
  const float* ff1_b       = (const float*)d_in[19];
  const float* ff2_w       = (const float*)d_in[20];
  const float* ff2_b       = (const float*)d_in[21];
  const float* out_w       = (const float*)d_in[22];
  const float* out_b       = (const float*)d_in[23];
  const int*   tgt         = (const int*)d_in[24];

  char* ws = (char*)d_ws;
  u16*   XB    = (u16*)(ws + XB_OFF);
  u16*   P     = (u16*)(ws + P_OFF);
  u16*   BIG   = (u16*)(ws + BIG_OFF);
  u16*   ATT   = (u16*)(ws + ATT_OFF);
  u16*   WSA   = (u16*)(ws + WSA_OFF);
  u16*   WSO   = (u16*)(ws + WSO_OFF);
  u16*   WCAV  = (u16*)(ws + WCAV_OFF);
  u16*   WCO   = (u16*)(ws + WCO_OFF);
  u16*   WF1   = (u16*)(ws + WF1_OFF);
  u16*   WF2   = (u16*)(ws + WF2_OFF);
  u16*   WOUT  = (u16*)(ws + WOUT_OFF);
  float* BOUT  = (float*)(ws + BOUT_OFF);
  u16*   MEMB  = (u16*)(ws + MEMB_OFF);
  u16*   CATMP = (u16*)(ws + CATMP_OFF);
  float* CAV   = (float*)(ws + CAV_OFF);

  // ---- weight conversion ----
  cvt_bf16_k<<<dim3(4608), dim3(256), 0, stream>>>(sa_inw, WSA, 1179648);
  cvt_bf16_k<<<dim3(1536), dim3(256), 0, stream>>>(sa_outw, WSO, 393216);
  cvt_ca_v_k<<<dim3(1536), dim3(256), 0, stream>>>(ca_inw, WCAV);
  cvt_bf16_k<<<dim3(1536), dim3(256), 0, stream>>>(ca_outw, WCO, 393216);
  cvt_bf16_k<<<dim3(6144), dim3(256), 0, stream>>>(ff1_w, WF1, 1572864);
  cvt_bf16_k<<<dim3(6144), dim3(256), 0, stream>>>(ff2_w, WF2, 1572864);
  cvt_outw_k<<<dim3(576), dim3(256), 0, stream>>>(out_w, WOUT);
  cvt_outb_k<<<dim3(5), dim3(256), 0, stream>>>(out_b, BOUT);
  cvt_memb_k<<<dim3(128), dim3(256), 0, stream>>>(encoder_out, MEMB);

  // ---- embedding (bf16 only) ----
  embed_k<<<dim3(MTOT / 4), dim3(256), 0, stream>>>(emb, point_out, pos, tgt, XB);

  // ---- cross-attention vectors, all 6 layers (independent of x) ----
  gemm_bt<64><<<dim3(4, 4, 6), dim3(256), 0, stream>>>(
      MEMB, WCAV, ca_inb + 1024, nullptr, CATMP,
      256, 512, 512, 512, 512, 0,
      0L, 262144L, 1536L, 131072L);
  gemm_bt<64><<<dim3(4, 4, 6), dim3(256), 0, stream>>>(
      CATMP, WCO, ca_outb, CAV, nullptr,
      256, 512, 512, 512, 512, 0,
      131072L, 262144L, 512L, 131072L);

  for (int l = 0; l < 6; ++l) {
    // QKV
    gemm_bt<128><<<dim3(12, 122, 1), dim3(256), 0, stream>>>(
        XB, WSA + (long)l * 786432, sa_inb + l * 1536, nullptr, BIG,
        MTOT, 1536, 512, 1536, 1536, 0, 0L, 0L, 0L, 0L);
    // fused attention
    attn_k<<<dim3(2048), dim3(256), 0, stream>>>(BIG, tgt, ATT);
    // out-proj (raw, bias only) -> P bf16
    gemm_bt<64><<<dim3(4, 244, 1), dim3(256), 0, stream>>>(
        ATT, WSO + (long)l * 262144, sa_outb + l * 512, nullptr, P,
        MTOT, 512, 512, 512, 512, 0, 0L, 0L, 0L, 0L);
    // fused resid + LN1 + CA add + LN2 -> XB
    lnf_k<true><<<dim3(MTOT / 4), dim3(256), 0, stream>>>(
        P, XB, CAV + (long)l * 131072,
        ln1_s + l * 512, ln1_b + l * 512, ln2_s + l * 512, ln2_b + l * 512, XB);
    // FF1 + ReLU -> h1 (bf16)
    gemm_bt<128><<<dim3(16, 122, 1), dim3(256), 0, stream>>>(
        XB, WF1 + (long)l * 1048576, ff1_b + l * 2048, nullptr, BIG,
        MTOT, 2048, 512, 2048, 2048, 1, 0L, 0L, 0L, 0L);
    // FF2 (raw) -> P bf16
    gemm_bt<64><<<dim3(4, 244, 1), dim3(256), 0, stream>>>(
        BIG, WF2 + (long)l * 1048576, ff2_b + l * 512, nullptr, P,
        MTOT, 512, 2048, 512, 512, 0, 0L, 0L, 0L, 0L);
    // fused resid + LN3 -> XB
    lnf_k<false><<<dim3(MTOT / 4), dim3(256), 0, stream>>>(
        P, XB, nullptr, ln3_s + l * 512, ln3_b + l * 512, nullptr, nullptr, XB);
  }

  // ---- final logits: [15616][1027] f32 ----
  gemm_bt<128><<<dim3(9, 122, 1), dim3(256), 0, stream>>>(
      XB, WOUT, BOUT, (float*)d_out, nullptr,
      MTOT, 1152, 512, 1027, 1027, 0, 0L, 0L, 0L, 0L);
}

// Round 4
// 1187.151 us; speedup vs baseline: 1.4495x; 1.0243x over previous
//
#include <hip/hip_runtime.h>
#include <stdint.h>
#include <stddef.h>

typedef unsigned short u16;
typedef float f4 __attribute__((ext_vector_type(4)));
typedef float f32x4 __attribute__((ext_vector_type(4)));
typedef short bf16x8 __attribute__((ext_vector_type(8)));
typedef u16 u16x4 __attribute__((ext_vector_type(4)));
typedef int i4v __attribute__((ext_vector_type(4)));

#define PAD_TOK 1026
#define LQ 61
#define NBATCH 256
#define MTOT (NBATCH * LQ)   // 15616 = 61*256 = 122*128 = 244*64

__device__ __forceinline__ u16 f2b(float f) {
  uint32_t x = __float_as_uint(f);
  x += 0x7fff + ((x >> 16) & 1);   // RNE
  return (u16)(x >> 16);
}
__device__ __forceinline__ float b2f(u16 u) {
  return __uint_as_float(((uint32_t)u) << 16);
}

#define GLDS(gptr, lptr) __builtin_amdgcn_global_load_lds( \
    (const __attribute__((address_space(1))) void*)(gptr), \
    (__attribute__((address_space(3))) void*)(lptr), 16, 0, 0)

__device__ __forceinline__ bf16x8 ldfrag(const u16* buf, int row, int ksl, int kg) {
  const int chunk = (ksl * 4 + kg) ^ (row & 7);
  return *(const bf16x8*)&buf[row * 64 + chunk * 8];
}

// ---------------------------------------------------------------------------
// 256x256 8-phase GEMM (T2+T3+T4+T5). BK=64, 2 K-tiles/iter, 8 waves (2Mx4N),
// wave output 128x64. Double-buffered LDS A/B (128 KiB). Counted vmcnt(7)
// gates at ph1/ph5 only; A staged quarter-tile into the region that died at
// the previous phase barrier; B staged right after its single-phase read.
// K must be a multiple of 128. M multiple of 256. N multiple of 256.
// ---------------------------------------------------------------------------
__global__ __launch_bounds__(512, 2) void gemm8_k(
    const u16* __restrict__ A, const u16* __restrict__ W,
    const float* __restrict__ bias,
    float* __restrict__ Cf, u16* __restrict__ Cb,
    int N, int K, int Nreal, int ldc, int relu)
{
  __shared__ u16 lds[4][16384];   // A0,B0,A1,B1 (32 KB each)
  u16* const LA0 = lds[0];
  u16* const LB0 = lds[1];
  u16* const LA1 = lds[2];
  u16* const LB1 = lds[3];

  // bijective XCD swizzle (m204)
  const int gx = gridDim.x;
  const int nwg = gx * gridDim.y;
  const int orig = blockIdx.y * gx + blockIdx.x;
  const int q8 = nwg >> 3, r8 = nwg & 7;
  const int xcd = orig & 7, off = orig >> 3;
  const int nid = (xcd < r8 ? xcd * (q8 + 1) : r8 * (q8 + 1) + (xcd - r8) * q8) + off;
  const int bx = nid % gx, by = nid / gx;

  const int tid = threadIdx.x;
  const int wid = tid >> 6, lane = tid & 63;
  const int wm = wid >> 2, wn = wid & 3;
  const long m0 = (long)by * 256;
  const long n0 = (long)bx * 256;

  const int lr = lane >> 3, lc = lane & 7;
  const int scol = ((lc ^ lr) << 3);          // pre-swizzled source col
  const int r = lane & 15, kg = lane >> 4;

  const u16* __restrict__ Ab = A + m0 * K;
  const u16* __restrict__ Wb = W + n0 * K;

  f32x4 acc[8][4];
#pragma unroll
  for (int i = 0; i < 8; ++i)
#pragma unroll
    for (int j = 0; j < 4; ++j) acc[i][j] = (f32x4){0.f, 0.f, 0.f, 0.f};

  // stage 64 rows [r0,r0+64) of gbase at k-offset kt (1 vmcnt unit/wave)
#define ST64(gbase, kt, ldsbuf, r0) do {                                     \
    const int rb_ = (r0) + wid * 8;                                          \
    GLDS((gbase) + (long)(rb_ + lr) * K + (kt) + scol, &(ldsbuf)[rb_ * 64]); \
  } while (0)
  // stage A-quadrant q_ (rows q*32..+32 and 128+q*32..+32), 1 unit/wave
#define STAQ(kt, ldsbuf, q_) do {                                            \
    const int rb_ = ((wid & 4) ? 128 : 0) + (q_) * 32 + (wid & 3) * 8;       \
    GLDS(Ab + (long)(rb_ + lr) * K + (kt) + scol, &(ldsbuf)[rb_ * 64]);      \
  } while (0)
#define STB(kt, ldsbuf) do {            \
    ST64(Wb, kt, ldsbuf, 0);   ST64(Wb, kt, ldsbuf, 64);  \
    ST64(Wb, kt, ldsbuf, 128); ST64(Wb, kt, ldsbuf, 192); \
  } while (0)
#define STAF(kt, ldsbuf) do {           \
    ST64(Ab, kt, ldsbuf, 0);   ST64(Ab, kt, ldsbuf, 64);  \
    ST64(Ab, kt, ldsbuf, 128); ST64(Ab, kt, ldsbuf, 192); \
  } while (0)
#define ENDBAR do { __builtin_amdgcn_sched_barrier(0); __builtin_amdgcn_s_barrier(); } while (0)
  // one phase: read A-quadrant q_ frags, 16 MFMA against held B frags
#define PHASE(bufA, q_) do {                                                 \
    bf16x8 a_[2][2];                                                         \
    _Pragma("unroll")                                                        \
    for (int ml = 0; ml < 2; ++ml)                                           \
      _Pragma("unroll")                                                      \
      for (int ks = 0; ks < 2; ++ks)                                         \
        a_[ml][ks] = ldfrag(bufA, wm * 128 + ((q_) * 2 + ml) * 16 + r, ks, kg); \
    __builtin_amdgcn_s_setprio(1);                                           \
    _Pragma("unroll")                                                        \
    for (int ml = 0; ml < 2; ++ml)                                           \
      _Pragma("unroll")                                                      \
      for (int ni = 0; ni < 4; ++ni) {                                       \
        acc[(q_) * 2 + ml][ni] = __builtin_amdgcn_mfma_f32_16x16x32_bf16(    \
            a_[ml][0], bf[ni][0], acc[(q_) * 2 + ml][ni], 0, 0, 0);          \
        acc[(q_) * 2 + ml][ni] = __builtin_amdgcn_mfma_f32_16x16x32_bf16(    \
            a_[ml][1], bf[ni][1], acc[(q_) * 2 + ml][ni], 0, 0, 0);          \
      }                                                                      \
    __builtin_amdgcn_s_setprio(0);                                           \
  } while (0)

  // prologue: tiles 0 -> buf0, 1 -> buf1 (16 units/wave outstanding)
  STAF(0, LA0); STB(0, LB0);
  STAF(64, LA1); STB(64, LB1);

  const int nits = K >> 7;
  bf16x8 bf[4][2];

  for (int it = 0; it < nits; ++it) {
    const int kt1 = it * 128 + 64;
    const int ktA = it * 128 + 128;   // even tile -> buf0
    const int ktB = it * 128 + 192;   // odd tile  -> buf1
    const bool last = (it == nits - 1);

    // ---- PH1: gate tile 2i; stage tile 2i+1's A-q3 ----
    asm volatile("s_waitcnt vmcnt(7)" ::: "memory");
    ENDBAR;
    if (it > 0) STAQ(kt1, LA1, 3);
#pragma unroll
    for (int ni = 0; ni < 4; ++ni)
#pragma unroll
      for (int ks = 0; ks < 2; ++ks)
        bf[ni][ks] = ldfrag(LB0, wn * 64 + ni * 16 + r, ks, kg);
    PHASE(LA0, 0);
    ENDBAR;
    // ---- PH2 ----
    if (!last) { STAQ(ktA, LA0, 0); STB(ktA, LB0); }
    PHASE(LA0, 1);
    ENDBAR;
    // ---- PH3 ----
    if (!last) STAQ(ktA, LA0, 1);
    PHASE(LA0, 2);
    ENDBAR;
    // ---- PH4 ----
    if (!last) STAQ(ktA, LA0, 2);
    PHASE(LA0, 3);
    ENDBAR;
    // ---- PH5: gate tile 2i+1; stage tile 2i+2's A-q3 ----
    if (last) asm volatile("s_waitcnt vmcnt(0)" ::: "memory");
    else      asm volatile("s_waitcnt vmcnt(7)" ::: "memory");
    ENDBAR;
    if (!last) STAQ(ktA, LA0, 3);
#pragma unroll
    for (int ni = 0; ni < 4; ++ni)
#pragma unroll
      for (int ks = 0; ks < 2; ++ks)
        bf[ni][ks] = ldfrag(LB1, wn * 64 + ni * 16 + r, ks, kg);
    PHASE(LA1, 0);
    ENDBAR;
    // ---- PH6 ----
    if (!last) { STAQ(ktB, LA1, 0); STB(ktB, LB1); }
    PHASE(LA1, 1);
    ENDBAR;
    // ---- PH7 ----
    if (!last) STAQ(ktB, LA1, 1);
    PHASE(LA1, 2);
    ENDBAR;
    // ---- PH8 ----
    if (!last) STAQ(ktB, LA1, 2);
    PHASE(LA1, 3);
    ENDBAR;
  }

  // ---- epilogue ----
  const int cr4 = (lane >> 4) * 4;
  const int cc = lane & 15;
  if (Cb) {
    u16* cbuf = &lds[0][0];   // 256x256 bf16, chunk-XOR swizzled
#pragma unroll
    for (int ni = 0; ni < 4; ++ni) {
      const int coll = wn * 64 + ni * 16 + cc;
      const float bv = bias[(int)n0 + coll];
#pragma unroll
      for (int mi = 0; mi < 8; ++mi) {
#pragma unroll
        for (int j = 0; j < 4; ++j) {
          const int rowl = wm * 128 + mi * 16 + cr4 + j;
          float v = acc[mi][ni][j] + bv;
          if (relu) v = fmaxf(v, 0.f);
          const int ch = coll >> 3;
          const int phys = ch ^ (rowl & 31);
          cbuf[rowl * 256 + phys * 8 + (coll & 7)] = f2b(v);
        }
      }
    }
    ENDBAR;
#pragma unroll
    for (int i = 0; i < 16; ++i) {
      const int t = i * 512 + tid;
      const int row = t >> 5, ch = t & 31;
      const int n = (int)n0 + ch * 8;
      if (n < Nreal) {
        const int phys = ch ^ (row & 31);
        *(bf16x8*)&Cb[(m0 + row) * (long)N + n] =
            *(const bf16x8*)&cbuf[row * 256 + phys * 8];
      }
    }
  } else {
#pragma unroll
    for (int ni = 0; ni < 4; ++ni) {
      const int n = (int)n0 + wn * 64 + ni * 16 + cc;
      if (n >= Nreal) continue;
      const float bv = bias[n];
#pragma unroll
      for (int mi = 0; mi < 8; ++mi) {
#pragma unroll
        for (int j = 0; j < 4; ++j) {
          const long m = m0 + wm * 128 + mi * 16 + cr4 + j;
          float v = acc[mi][ni][j] + bv;
          if (relu) v = fmaxf(v, 0.f);
          Cf[m * ldc + n] = v;
        }
      }
    }
  }
#undef ST64
#undef STAQ
#undef STB
#undef STAF
#undef ENDBAR
#undef PHASE
}

// ---------------------------------------------------------------------------
// bf16 B^T GEMM, BM x 128 tile, BK=64, 4 waves (small-N / small-M cases).
// ---------------------------------------------------------------------------
template<int BM>
__global__ __launch_bounds__(256) void gemm_bt(
    const u16* __restrict__ A, const u16* __restrict__ W,
    const float* __restrict__ bias,
    float* __restrict__ Cf, u16* __restrict__ Cb,
    int M, int N, int K, int Nreal, int ldc, int relu,
    long aZ, long wZ, long bZ, long cZ)
{
  constexpr int MI = BM / 32;
  const int z = blockIdx.z;
  A += z * aZ; W += z * wZ; bias += z * bZ;
  if (Cf) Cf += z * cZ;
  if (Cb) Cb += z * cZ;

  __shared__ u16 As[BM * 64];
  __shared__ u16 Bs[128 * 64];

  const int gx = gridDim.x;
  const int nwg = gx * gridDim.y;
  const int orig = blockIdx.y * gx + blockIdx.x;
  const int q8 = nwg >> 3, r8 = nwg & 7;
  const int xcd = orig & 7, off = orig >> 3;
  const int nid = (xcd < r8 ? xcd * (q8 + 1) : r8 * (q8 + 1) + (xcd - r8) * q8) + off;
  const int bx = nid % gx, by = nid / gx;

  const int tid = threadIdx.x;
  const int wid = tid >> 6, lane = tid & 63;
  const int wr = wid >> 1, wc = wid & 1;
  const long m0 = (long)by * BM;
  const long n0 = (long)bx * 128;

  const int lr = lane >> 3;
  const int lc = lane & 7;
  const int scol = ((lc ^ lr) << 3);

  f32x4 acc[MI][4];
#pragma unroll
  for (int i = 0; i < MI; ++i)
#pragma unroll
    for (int j = 0; j < 4; ++j) acc[i][j] = (f32x4){0.f, 0.f, 0.f, 0.f};

  const u16* Abase = A + m0 * K;
  const u16* Wbase = W + n0 * K;
  const int r = lane & 15, kg = lane >> 4;

  for (int kt = 0; kt < K; kt += 64) {
#pragma unroll
    for (int c = 0; c < BM / 32; ++c) {
      const int row = wid * (BM / 4) + c * 8;
      __builtin_amdgcn_global_load_lds(
          (const __attribute__((address_space(1))) void*)(Abase + (long)(row + lr) * K + kt + scol),
          (__attribute__((address_space(3))) void*)&As[row * 64], 16, 0, 0);
    }
#pragma unroll
    for (int c = 0; c < 4; ++c) {
      const int row = wid * 32 + c * 8;
      __builtin_amdgcn_global_load_lds(
          (const __attribute__((address_space(1))) void*)(Wbase + (long)(row + lr) * K + kt + scol),
          (__attribute__((address_space(3))) void*)&Bs[row * 64], 16, 0, 0);
    }
    __syncthreads();

#pragma unroll
    for (int ks = 0; ks < 64; ks += 32) {
      bf16x8 a[MI], b[4];
#pragma unroll
      for (int mi = 0; mi < MI; ++mi) {
        const int row = wr * (BM / 2) + mi * 16 + r;
        const int chunk = ((ks >> 3) + kg) ^ (row & 7);
        a[mi] = *(const bf16x8*)&As[row * 64 + chunk * 8];
      }
#pragma unroll
      for (int ni = 0; ni < 4; ++ni) {
        const int row = wc * 64 + ni * 16 + r;
        const int chunk = ((ks >> 3) + kg) ^ (row & 7);
        b[ni] = *(const bf16x8*)&Bs[row * 64 + chunk * 8];
      }
#pragma unroll
      for (int mi = 0; mi < MI; ++mi)
#pragma unroll
        for (int ni = 0; ni < 4; ++ni)
          acc[mi][ni] = __builtin_amdgcn_mfma_f32_16x16x32_bf16(a[mi], b[ni], acc[mi][ni], 0, 0, 0);
    }
    __syncthreads();
  }

  const int cr4 = (lane >> 4) * 4;
  const int cc = lane & 15;

  if (Cb) {
#pragma unroll
    for (int ni = 0; ni < 4; ++ni) {
      const int coll = wc * 64 + ni * 16 + cc;
      const float bv = bias[(int)n0 + coll];
#pragma unroll
      for (int mi = 0; mi < MI; ++mi) {
#pragma unroll
        for (int j = 0; j < 4; ++j) {
          const int rowl = wr * (BM / 2) + mi * 16 + cr4 + j;
          float v = acc[mi][ni][j] + bv;
          if (relu) v = fmaxf(v, 0.f);
          const int sw = (rowl & 7) << 3;
          u16* half = (coll & 64) ? Bs : As;
          half[rowl * 64 + ((coll & 63) ^ sw)] = f2b(v);
        }
      }
    }
    __syncthreads();
    constexpr int PT = BM / 16;
#pragma unroll
    for (int i = 0; i < PT; ++i) {
      const int t = i * 256 + tid;
      const int row = t >> 4, ch = t & 15;
      const int n = (int)n0 + ch * 8;
      if (n < Nreal) {
        const int phys = (ch & 7) ^ (row & 7);
        const u16* half = (ch < 8) ? As : Bs;
        bf16x8 vv = *(const bf16x8*)&half[row * 64 + phys * 8];
        *(bf16x8*)&Cb[(m0 + row) * (long)N + n] = vv;
      }
    }
  } else {
#pragma unroll
    for (int ni = 0; ni < 4; ++ni) {
      const int n = (int)n0 + wc * 64 + ni * 16 + cc;
      if (n >= Nreal) continue;
      const float bv = bias[n];
#pragma unroll
      for (int mi = 0; mi < MI; ++mi) {
#pragma unroll
        for (int j = 0; j < 4; ++j) {
          const long m = m0 + wr * (BM / 2) + mi * 16 + cr4 + j;
          float v = acc[mi][ni][j] + bv;
          if (relu) v = fmaxf(v, 0.f);
          Cf[m * ldc + n] = v;
        }
      }
    }
  }
}

// ---------------------------------------------------------------------------
// Fused self-attention: one block per (batch, head).
// ---------------------------------------------------------------------------
__global__ __launch_bounds__(256) void attn_k(const u16* __restrict__ qkv,
                                              const int* __restrict__ tgt,
                                              u16* __restrict__ outp)
{
  __shared__ u16 Qs[64 * 72];
  __shared__ u16 Ks[64 * 72];
  __shared__ u16 Vt[64 * 72];
  __shared__ float S[64 * 65];
  __shared__ int stok[64];

  const int bid = blockIdx.x;
  const int b = bid >> 3, h = bid & 7;
  const int tid = threadIdx.x;
  const int tr = tid >> 2, seg = tid & 3;

  if (tid < 64) stok[tid] = (tid < 61) ? tgt[b * 62 + tid] : -1;

  const long rowbase = ((long)(b * LQ + tr)) * 1536 + h * 64;
  if (tr < LQ) {
    const i4v* qsrc = (const i4v*)(qkv + rowbase + seg * 16);
    i4v q0 = qsrc[0], q1 = qsrc[1];
    *(i4v*)&Qs[tr * 72 + seg * 16] = q0;
    *(i4v*)&Qs[tr * 72 + seg * 16 + 8] = q1;
    const i4v* ksrc = (const i4v*)(qkv + rowbase + 512 + seg * 16);
    i4v k0 = ksrc[0], k1 = ksrc[1];
    *(i4v*)&Ks[tr * 72 + seg * 16] = k0;
    *(i4v*)&Ks[tr * 72 + seg * 16 + 8] = k1;
    const u16* vsrc = qkv + rowbase + 1024 + seg * 16;
#pragma unroll
    for (int i = 0; i < 16; ++i) Vt[(seg * 16 + i) * 72 + tr] = vsrc[i];
  } else {
    i4v zz = {0, 0, 0, 0};
    *(i4v*)&Qs[tr * 72 + seg * 16] = zz;
    *(i4v*)&Qs[tr * 72 + seg * 16 + 8] = zz;
    *(i4v*)&Ks[tr * 72 + seg * 16] = zz;
    *(i4v*)&Ks[tr * 72 + seg * 16 + 8] = zz;
#pragma unroll
    for (int i = 0; i < 16; ++i) Vt[(seg * 16 + i) * 72 + tr] = 0;
  }
  __syncthreads();

  const int lane = tid & 63, w = tid >> 6;
  const int r = lane & 15, kg = lane >> 4;

  {   // QK^T
    f32x4 s[4];
#pragma unroll
    for (int ni = 0; ni < 4; ++ni) s[ni] = (f32x4){0.f, 0.f, 0.f, 0.f};
    bf16x8 a0 = *(const bf16x8*)&Qs[(w * 16 + r) * 72 + kg * 8];
    bf16x8 a1 = *(const bf16x8*)&Qs[(w * 16 + r) * 72 + 32 + kg * 8];
#pragma unroll
    for (int ni = 0; ni < 4; ++ni) {
      bf16x8 b0 = *(const bf16x8*)&Ks[(ni * 16 + r) * 72 + kg * 8];
      bf16x8 b1 = *(const bf16x8*)&Ks[(ni * 16 + r) * 72 + 32 + kg * 8];
      s[ni] = __builtin_amdgcn_mfma_f32_16x16x32_bf16(a0, b0, s[ni], 0, 0, 0);
      s[ni] = __builtin_amdgcn_mfma_f32_16x16x32_bf16(a1, b1, s[ni], 0, 0, 0);
    }
#pragma unroll
    for (int ni = 0; ni < 4; ++ni)
#pragma unroll
      for (int j = 0; j < 4; ++j)
        S[(w * 16 + kg * 4 + j) * 65 + ni * 16 + r] = s[ni][j];
  }
  __syncthreads();

  {   // masked softmax
    const int row = tid >> 2, g = tid & 3;
    float vals[16];
    float mx = -3e38f;
#pragma unroll
    for (int i = 0; i < 16; ++i) {
      const int k = g * 16 + i;
      float v = S[row * 65 + k] * 0.125f;
      const bool ok = (k <= row) && (k < LQ) && (stok[k] != PAD_TOK);
      v = ok ? v : -1e30f;
      vals[i] = v;
      mx = fmaxf(mx, v);
    }
    mx = fmaxf(mx, __shfl_xor(mx, 1));
    mx = fmaxf(mx, __shfl_xor(mx, 2));
    float sum = 0.f;
#pragma unroll
    for (int i = 0; i < 16; ++i) { float e = __expf(vals[i] - mx); vals[i] = e; sum += e; }
    sum += __shfl_xor(sum, 1);
    sum += __shfl_xor(sum, 2);
    const float inv = 1.f / sum;
#pragma unroll
    for (int i = 0; i < 16; ++i) Qs[row * 72 + g * 16 + i] = f2b(vals[i] * inv);
  }
  __syncthreads();

  {   // PV, swizzled bounce into Ks
    f32x4 o[4];
#pragma unroll
    for (int ni = 0; ni < 4; ++ni) o[ni] = (f32x4){0.f, 0.f, 0.f, 0.f};
    bf16x8 a0 = *(const bf16x8*)&Qs[(w * 16 + r) * 72 + kg * 8];
    bf16x8 a1 = *(const bf16x8*)&Qs[(w * 16 + r) * 72 + 32 + kg * 8];
#pragma unroll
    for (int ni = 0; ni < 4; ++ni) {
      bf16x8 b0 = *(const bf16x8*)&Vt[(ni * 16 + r) * 72 + kg * 8];
      bf16x8 b1 = *(const bf16x8*)&Vt[(ni * 16 + r) * 72 + 32 + kg * 8];
      o[ni] = __builtin_amdgcn_mfma_f32_16x16x32_bf16(a0, b0, o[ni], 0, 0, 0);
      o[ni] = __builtin_amdgcn_mfma_f32_16x16x32_bf16(a1, b1, o[ni], 0, 0, 0);
    }
#pragma unroll
    for (int ni = 0; ni < 4; ++ni)
#pragma unroll
      for (int j = 0; j < 4; ++j) {
        const int qrow = w * 16 + kg * 4 + j;
        const int col = ni * 16 + r;
        Ks[qrow * 64 + (col ^ ((qrow & 7) << 3))] = f2b(o[ni][j]);
      }
  }
  __syncthreads();

  {   // coalesced O store
    const int row = tid >> 2, sub = tid & 3;
    if (row < LQ) {
      const long obase = ((long)(b * LQ + row)) * 512 + h * 64;
#pragma unroll
      for (int i = 0; i < 2; ++i) {
        const int ch = i * 4 + sub;
        const int phys = ch ^ (row & 7);
        bf16x8 vv = *(const bf16x8*)&Ks[row * 64 + phys * 8];
        *(bf16x8*)&outp[obase + ch * 8] = vv;
      }
    }
  }
}

__device__ __forceinline__ void ln_row(f4& v0, f4& v1,
                                       const float* __restrict__ sw,
                                       const float* __restrict__ bw, int d0) {
  float s1 = v0[0] + v0[1] + v0[2] + v0[3] + v1[0] + v1[1] + v1[2] + v1[3];
  float s2 = v0[0]*v0[0] + v0[1]*v0[1] + v0[2]*v0[2] + v0[3]*v0[3]
           + v1[0]*v1[0] + v1[1]*v1[1] + v1[2]*v1[2] + v1[3]*v1[3];
#pragma unroll
  for (int off = 1; off < 64; off <<= 1) {
    s1 += __shfl_xor(s1, off);
    s2 += __shfl_xor(s2, off);
  }
  const float mean = s1 * (1.f / 512.f);
  const float var = s2 * (1.f / 512.f) - mean * mean;
  const float rstd = rsqrtf(var + 1e-5f);
  const f4* sp = (const f4*)(sw + d0);
  const f4* bp = (const f4*)(bw + d0);
  f4 ss0 = sp[0], ss1 = sp[1], bb0 = bp[0], bb1 = bp[1];
#pragma unroll
  for (int i = 0; i < 4; ++i) {
    v0[i] = (v0[i] - mean) * rstd * ss0[i] + bb0[i];
    v1[i] = (v1[i] - mean) * rstd * ss1[i] + bb1[i];
  }
}

template<bool CA>
__global__ __launch_bounds__(256) void lnf_k(const u16* __restrict__ p,
                                             const u16* __restrict__ xr,
                                             const float* __restrict__ cav,
                                             const float* __restrict__ s1,
                                             const float* __restrict__ b1,
                                             const float* __restrict__ s2,
                                             const float* __restrict__ b2,
                                             u16* __restrict__ out)
{
  const int m = blockIdx.x * 4 + (threadIdx.x >> 6);
  const int lane = threadIdx.x & 63;
  const int d0 = lane * 8;
  bf16x8 pv = *(const bf16x8*)(p + (long)m * 512 + d0);
  bf16x8 xv = *(const bf16x8*)(xr + (long)m * 512 + d0);
  f4 v0, v1;
#pragma unroll
  for (int i = 0; i < 4; ++i) {
    v0[i] = b2f((u16)pv[i]) + b2f((u16)xv[i]);
    v1[i] = b2f((u16)pv[4 + i]) + b2f((u16)xv[4 + i]);
  }
  ln_row(v0, v1, s1, b1, d0);
  if constexpr (CA) {
    const int b = m / LQ;
    const f4* qv = (const f4*)(cav + (long)b * 512 + d0);
    v0 += qv[0]; v1 += qv[1];
    ln_row(v0, v1, s2, b2, d0);
  }
  u16x4* ob = (u16x4*)(out + (long)m * 512 + d0);
  ob[0] = (u16x4){f2b(v0[0]), f2b(v0[1]), f2b(v0[2]), f2b(v0[3])};
  ob[1] = (u16x4){f2b(v1[0]), f2b(v1[1]), f2b(v1[2]), f2b(v1[3])};
}

__global__ __launch_bounds__(256) void embed_k(const float* __restrict__ emb,
                                               const float* __restrict__ pout,
                                               const float* __restrict__ pos,
                                               const int* __restrict__ tgt,
                                               u16* __restrict__ XB)
{
  const int m = blockIdx.x * 4 + (threadIdx.x >> 6);
  const int lane = threadIdx.x & 63;
  const int b = m / LQ, t = m % LQ;
  const int tok = tgt[b * 62 + t];
  const int d0 = lane * 8;
  const f4* e = (const f4*)(emb + (long)tok * 512 + d0);
  const f4* p = (const f4*)(pout + (long)b * 512 + d0);
  const f4* q = (const f4*)(pos + (long)t * 512 + d0);
  f4 v0 = e[0] + p[0] + q[0];
  f4 v1 = e[1] + p[1] + q[1];
  u16x4* xb = (u16x4*)(XB + (long)m * 512 + d0);
  xb[0] = (u16x4){f2b(v0[0]), f2b(v0[1]), f2b(v0[2]), f2b(v0[3])};
  xb[1] = (u16x4){f2b(v1[0]), f2b(v1[1]), f2b(v1[2]), f2b(v1[3])};
}

__global__ void cvt_bf16_k(const float* __restrict__ src, u16* __restrict__ dst, int n4) {
  const int i = blockIdx.x * 256 + threadIdx.x;
  if (i >= n4) return;
  f4 v = ((const f4*)src)[i];
  ((u16x4*)dst)[i] = (u16x4){f2b(v[0]), f2b(v[1]), f2b(v[2]), f2b(v[3])};
}

__global__ void cvt_ca_v_k(const float* __restrict__ ca_inw, u16* __restrict__ dst) {
  const int i = blockIdx.x * 256 + threadIdx.x;
  if (i >= 393216) return;
  const int l = i >> 16, rem = i & 65535;
  f4 v = ((const f4*)ca_inw)[l * 196608 + 131072 + rem];
  ((u16x4*)dst)[i] = (u16x4){f2b(v[0]), f2b(v[1]), f2b(v[2]), f2b(v[3])};
}

// out_w padded to [1280][512] bf16, rows >=1027 zero
__global__ void cvt_outw_k(const float* __restrict__ out_w, u16* __restrict__ dst) {
  const int i = blockIdx.x * 256 + threadIdx.x;
  if (i >= 163840) return;                  // 1280*512/4
  const int row = (i * 4) >> 9;
  u16x4 o = {0, 0, 0, 0};
  if (row < 1027) {
    f4 v = ((const f4*)out_w)[i];
    o = (u16x4){f2b(v[0]), f2b(v[1]), f2b(v[2]), f2b(v[3])};
  }
  ((u16x4*)dst)[i] = o;
}

__global__ void cvt_outb_k(const float* __restrict__ out_b, float* __restrict__ dst) {
  const int i = blockIdx.x * 256 + threadIdx.x;
  if (i >= 1280) return;
  dst[i] = (i < 1027) ? out_b[i] : 0.f;
}

__global__ void cvt_memb_k(const float* __restrict__ enc, u16* __restrict__ dst) {
  const int i = blockIdx.x * 256 + threadIdx.x;
  if (i >= 32768) return;
  const int b = (i * 4) >> 9, d = (i * 4) & 511;
  f4 v = ((const f4*)enc)[(b * 8192 + d) >> 2];
  ((u16x4*)dst)[i] = (u16x4){f2b(v[0]), f2b(v[1]), f2b(v[2]), f2b(v[3])};
}

// ---------------------------------------------------------------------------
// Workspace layout (bytes)
// ---------------------------------------------------------------------------
static constexpr size_t XB_OFF    = 0;            // bf16 [15616][512]
static constexpr size_t P_OFF     = 15990784;     // bf16 [15616][512]
static constexpr size_t BIG_OFF   = 31981568;     // bf16 qkv/h1
static constexpr size_t ATT_OFF   = 95944704;     // bf16 [15616][512]
static constexpr size_t WSA_OFF   = 111935488;    // bf16 [6][1536][512]
static constexpr size_t WSO_OFF   = 121372672;    // bf16 [6][512][512]
static constexpr size_t WCAV_OFF  = 124518400;    // bf16 [6][512][512]
static constexpr size_t WCO_OFF   = 127664128;    // bf16 [6][512][512]
static constexpr size_t WF1_OFF   = 130809856;    // bf16 [6][2048][512]
static constexpr size_t WF2_OFF   = 143392768;    // bf16 [6][512][2048]
static constexpr size_t WOUT_OFF  = 155975680;    // bf16 [1280][512]
static constexpr size_t BOUT_OFF  = 157286400;    // f32  [1280]
static constexpr size_t MEMB_OFF  = 157291520;    // bf16 [256][512]
static constexpr size_t CATMP_OFF = 157553664;    // bf16 [6][256][512]
static constexpr size_t CAV_OFF   = 159126528;    // f32  [6][256][512]

extern "C" void kernel_launch(void* const* d_in, const int* in_sizes, int n_in,
                              void* d_out, int out_size, void* d_ws, size_t ws_size,
                              hipStream_t stream) {
  (void)in_sizes; (void)n_in; (void)out_size; (void)ws_size;
  const float* encoder_out = (const float*)d_in[0];
  const float* point_out   = (const float*)d_in[1];
  const float* emb         = (const float*)d_in[2];
  const float* pos         = (const float*)d_in[3];
  const float* sa_inw      = (const float*)d_in[4];
  const float* sa_inb      = (const float*)d_in[5];
  const float* sa_outw     = (const float*)d_in[6];
  const float* sa_outb     = (const float*)d_in[7];
  const float* ca_inw      = (const float*)d_in[8];
  const float* ca_inb      = (const float*)d_in[9];
  const float* ca_outw     = (const float*)d_in[10];
  const float* ca_outb     = (const float*)d_in[11];
  const float* ln1_s       = (const float*)d_in[12];
  const float* ln1_b       = (const float*)d_in[13];
  const float* ln2_s       = (const float*)d_in[14];
  const float* ln2_b       = (const float*)d_in[15];
  const float* ln3_s       = (const float*)d_in[16];
  const float* ln3_b       = (const float*)d_in[17];
  const float* ff1_w       = (const float*)d_in[18];
  const float* ff1_b       = (const float*)d_in[19];
  const float* ff2_w       = (const float*)d_in[20];
  const float* ff2_b       = (const float*)d_in[21];
  const float* out_w       = (const float*)d_in[22];
  const float* out_b       = (const float*)d_in[23];
  const int*   tgt         = (const int*)d_in[24];

  char* ws = (char*)d_ws;
  u16*   XB    = (u16*)(ws + XB_OFF);
  u16*   P     = (u16*)(ws + P_OFF);
  u16*   BIG   = (u16*)(ws + BIG_OFF);
  u16*   ATT   = (u16*)(ws + ATT_OFF);
  u16*   WSA   = (u16*)(ws + WSA_OFF);
  u16*   WSO   = (u16*)(ws + WSO_OFF);
  u16*   WCAV  = (u16*)(ws + WCAV_OFF);
  u16*   WCO   = (u16*)(ws + WCO_OFF);
  u16*   WF1   = (u16*)(ws + WF1_OFF);
  u16*   WF2   = (u16*)(ws + WF2_OFF);
  u16*   WOUT  = (u16*)(ws + WOUT_OFF);
  float* BOUT  = (float*)(ws + BOUT_OFF);
  u16*   MEMB  = (u16*)(ws + MEMB_OFF);
  u16*   CATMP = (u16*)(ws + CATMP_OFF);
  float* CAV   = (float*)(ws + CAV_OFF);

  // ---- weight conversion ----
  cvt_bf16_k<<<dim3(4608), dim3(256), 0, stream>>>(sa_inw, WSA, 1179648);
  cvt_bf16_k<<<dim3(1536), dim3(256), 0, stream>>>(sa_outw, WSO, 393216);
  cvt_ca_v_k<<<dim3(1536), dim3(256), 0, stream>>>(ca_inw, WCAV);
  cvt_bf16_k<<<dim3(1536), dim3(256), 0, stream>>>(ca_outw, WCO, 393216);
  cvt_bf16_k<<<dim3(6144), dim3(256), 0, stream>>>(ff1_w, WF1, 1572864);
  cvt_bf16_k<<<dim3(6144), dim3(256), 0, stream>>>(ff2_w, WF2, 1572864);
  cvt_outw_k<<<dim3(640), dim3(256), 0, stream>>>(out_w, WOUT);
  cvt_outb_k<<<dim3(5), dim3(256), 0, stream>>>(out_b, BOUT);
  cvt_memb_k<<<dim3(128), dim3(256), 0, stream>>>(encoder_out, MEMB);

  // ---- embedding ----
  embed_k<<<dim3(MTOT / 4), dim3(256), 0, stream>>>(emb, point_out, pos, tgt, XB);

  // ---- cross-attention vectors (x-independent) ----
  gemm_bt<64><<<dim3(4, 4, 6), dim3(256), 0, stream>>>(
      MEMB, WCAV, ca_inb + 1024, nullptr, CATMP,
      256, 512, 512, 512, 512, 0,
      0L, 262144L, 1536L, 131072L);
  gemm_bt<64><<<dim3(4, 4, 6), dim3(256), 0, stream>>>(
      CATMP, WCO, ca_outb, CAV, nullptr,
      256, 512, 512, 512, 512, 0,
      131072L, 262144L, 512L, 131072L);

  for (int l = 0; l < 6; ++l) {
    // QKV: 256x256 8-phase, grid 6x61
    gemm8_k<<<dim3(6, 61), dim3(512), 0, stream>>>(
        XB, WSA + (long)l * 786432, sa_inb + l * 1536, nullptr, BIG,
        1536, 512, 1536, 1536, 0);
    // fused attention
    attn_k<<<dim3(2048), dim3(256), 0, stream>>>(BIG, tgt, ATT);
    // out-proj -> P bf16
    gemm_bt<64><<<dim3(4, 244, 1), dim3(256), 0, stream>>>(
        ATT, WSO + (long)l * 262144, sa_outb + l * 512, nullptr, P,
        MTOT, 512, 512, 512, 512, 0, 0L, 0L, 0L, 0L);
    // fused resid + LN1 + CA add + LN2 -> XB
    lnf_k<true><<<dim3(MTOT / 4), dim3(256), 0, stream>>>(
        P, XB, CAV + (long)l * 131072,
        ln1_s + l * 512, ln1_b + l * 512, ln2_s + l * 512, ln2_b + l * 512, XB);
    // FF1 + ReLU: 256x256 8-phase, grid 8x61
    gemm8_k<<<dim3(8, 61), dim3(512), 0, stream>>>(
        XB, WF1 + (long)l * 1048576, ff1_b + l * 2048, nullptr, BIG,
        2048, 512, 2048, 2048, 1);
    // FF2 -> P bf16
    gemm_bt<64><<<dim3(4, 244, 1), dim3(256), 0, stream>>>(
        BIG, WF2 + (long)l * 1048576, ff2_b + l * 512, nullptr, P,
        MTOT, 512, 2048, 512, 512, 0, 0L, 0L, 0L, 0L);
    // fused resid + LN3 -> XB
    lnf_k<false><<<dim3(MTOT / 4), dim3(256), 0, stream>>>(
        P, XB, nullptr, ln3_s + l * 512, ln3_b + l * 512, nullptr, nullptr, XB);
  }

  // ---- final logits: 256x256 8-phase, N padded to 1280, f32 out ----
  gemm8_k<<<dim3(5, 61), dim3(512), 0, stream>>>(
      XB, WOUT, BOUT, (float*)d_out, nullptr,
      1280, 512, 1027, 1027, 0);
}